// Round 14
// baseline (1143.310 us; speedup 1.0000x reference)
//
#include <hip/hip_runtime.h>
#include <cstdint>
#include <cstddef>

// ---------------- problem constants ----------------
#define BB 128
#define NMAP 32
#define NPRIM 144
#define NCAP 4608      // 32*144
#define NCLS 10
#define ODIM 16
#define IDIM 8

// ws layout (float offsets)
#define WS_X1H  0                       // x1 hi bf16 NHWC ushort; later reused for Wtv fp32 (5.9M fl)
#define WS_X1L  6553600                 // x1 lo bf16
#define WS_BH   13107200                // packed conv2 weights Bpk: [81 t][8 icc][2 comp][4 kq][256 oc][8] ushort
#define WS_P    18415616                // conv2 out NHWC: [128*144][256]
#define WS_U    23134208                // squash:   [128][4608][8]
#define WS_V    27852800                // routing v: [128][10][16]
#define WS_H1   27873280                // dec h1: [128][512]
#define WS_H2   27938816                // dec h2: [128][1024]
#define WS_CLS  28069888                // argmax class per b (int), 128

// out layout (floats): [128*10 onehot][128*784 reconst][128*10 v_length]
#define OUT_REC  1280
#define OUT_LEN  101632

typedef __attribute__((ext_vector_type(8))) short short8;
typedef __attribute__((ext_vector_type(4))) float f32x4;

// round-to-nearest-even fp32 -> bf16 bits
static __device__ __forceinline__ ushort f2bf(float f) {
    uint u = __float_as_uint(f);
    u = (u + 0x7FFFu + ((u >> 16) & 1u)) >> 16;
    return (ushort)u;
}
static __device__ __forceinline__ float bf2f(ushort h) {
    return __uint_as_float(((uint)h) << 16);
}

// async global->LDS, 16B per lane. Global addr is PER-LANE; LDS dest is
// wave-uniform base + lane*16 (HW-added).
static __device__ __forceinline__ void gload16(const ushort* g, ushort* l) {
    __builtin_amdgcn_global_load_lds(
        (const __attribute__((address_space(1))) void*)g,
        (__attribute__((address_space(3))) void*)l, 16, 0, 0);
}

// ---------------- kernels ----------------

// conv1 + bias + relu, emitting NHWC bf16 hi/lo directly.
__global__ __launch_bounds__(256) void k_conv1(const float* __restrict__ img,
                                               const float* __restrict__ w,
                                               const float* __restrict__ bias,
                                               ushort* __restrict__ x1h,
                                               ushort* __restrict__ x1l) {
    __shared__ float simg[252];   // 9 rows x 28 cols
    int bi = blockIdx.x;
    int y = bi % 20;
    int b = bi / 20;
    int oc = threadIdx.x;
    if (threadIdx.x < 252)
        simg[threadIdx.x] = img[(size_t)b * 784 + y * 28 + threadIdx.x];
    __syncthreads();

    float acc[20];
    float bv = bias[oc];
#pragma unroll
    for (int x = 0; x < 20; ++x) acc[x] = bv;
    const float* wp = w + oc * 81;
#pragma unroll
    for (int kh = 0; kh < 9; ++kh) {
        float r[28];
#pragma unroll
        for (int j = 0; j < 28; ++j) r[j] = simg[kh * 28 + j];
#pragma unroll
        for (int kw = 0; kw < 9; ++kw) {
            float wv = wp[kh * 9 + kw];
#pragma unroll
            for (int x = 0; x < 20; ++x)
                acc[x] = fmaf(wv, r[x + kw], acc[x]);
        }
    }
    size_t base = ((size_t)b * 400 + y * 20) * 256 + oc;
#pragma unroll
    for (int x = 0; x < 20; ++x) {
        float v = fmaxf(acc[x], 0.f);
        ushort h = f2bf(v);
        ushort lo = f2bf(v - bf2f(h));
        x1h[base + (size_t)x * 256] = h;
        x1l[base + (size_t)x * 256] = lo;
    }
}

// conv2 weights repack for LDS staging:
// w2[oc][ic][81] fp32 -> Bpk[t][icc][comp][kq][oc 256][ic8 8] bf16 hi/lo.
__global__ __launch_bounds__(256) void k_prep_w2(const float* __restrict__ w2,
                                                 ushort* __restrict__ bpk) {
    int blk = blockIdx.x;            // 256 = icc*32 + kq*8 + ocg
    int icc = blk >> 5, kq = (blk >> 3) & 3, ocg = blk & 7;
    int tid = threadIdx.x;
    int ocl = tid >> 3, ic8 = tid & 7;
    int oc = ocg * 32 + ocl;
    int ic = icc * 32 + kq * 8 + ic8;
    const float* src = w2 + ((size_t)oc * 256 + ic) * 81;
    size_t dbase = (size_t)icc * 16384 + (size_t)kq * 2048 + (size_t)oc * 8 + ic8;
#pragma unroll 9
    for (int t = 0; t < 81; ++t) {
        float v = src[t];
        ushort h = f2bf(v);
        ushort lo = f2bf(v - bf2f(h));
        bpk[(size_t)t * 131072 + dbase] = h;            // comp 0 (hi)
        bpk[(size_t)t * 131072 + dbase + 8192] = lo;    // comp 1 (lo)
    }
}

// ---- conv2: A slab + 6-deep async B ring + cross-phase REGISTER pipeline ----
// R11 verdict: 533us, MfmaUtil 49%. Three scheduling attacks all land
// 533-564 -> HIP-source ceiling for this barrier structure. FROZEN.
static __device__ __forceinline__ f32x4 mfma16(short8 a, short8 b, f32x4 c) {
    return __builtin_amdgcn_mfma_f32_16x16x32_bf16(a, b, c, 0, 0, 0);
}

struct FragR { short8 ah[5], al[5], bh0, bh1, bl0, bl1; };

template<int NMF>
static __device__ __forceinline__ void pre_fragR(
    FragR& f, const ushort* A_lds, const ushort* Bb, int tn,
    const int* celloff, int bro0, int bro1) {
    int kh = tn / 9, kw = tn - kh * 9;
    int tapoff = (kh * 20 + kw) * 40;
    const ushort* Bc = Bb + (tn % 6) * 8192;
#pragma unroll
    for (int i = 0; i < NMF; ++i) {
        f.ah[i] = *(const short8*)(A_lds + tapoff + celloff[i]);
        f.al[i] = *(const short8*)(A_lds + 16000 + tapoff + celloff[i]);
    }
    f.bh0 = *(const short8*)(Bc + bro0);
    f.bh1 = *(const short8*)(Bc + bro1);
    f.bl0 = *(const short8*)(Bc + 4096 + bro0);
    f.bl1 = *(const short8*)(Bc + 4096 + bro1);
}

template<int NMF>
static __device__ __forceinline__ void mfma_fragR(f32x4 (&acc)[5][2], const FragR& f) {
#pragma unroll
    for (int i = 0; i < NMF; ++i) {
        acc[i][0] = mfma16(f.ah[i], f.bh0, acc[i][0]);
        acc[i][1] = mfma16(f.ah[i], f.bh1, acc[i][1]);
    }
#pragma unroll
    for (int i = 0; i < NMF; ++i) {
        acc[i][0] = mfma16(f.ah[i], f.bl0, acc[i][0]);
        acc[i][1] = mfma16(f.ah[i], f.bl1, acc[i][1]);
    }
#pragma unroll
    for (int i = 0; i < NMF; ++i) {
        acc[i][0] = mfma16(f.al[i], f.bh0, acc[i][0]);
        acc[i][1] = mfma16(f.al[i], f.bh1, acc[i][1]);
    }
}

static __device__ __forceinline__ void stage_tap(
    const ushort* gB0, ushort* lB0, int tn, size_t gicc) {
    if (tn <= 80) {
        size_t g = (size_t)tn * 131072 + gicc;
        ushort* d = lB0 + (tn % 6) * 8192;
        gload16(gB0 + g, d);
        gload16(gB0 + g + 512, d + 512);
    }
}

template<int MF0, int NMF>
static __device__ __forceinline__ void conv2s_epi(
    const f32x4 (&acc)[5][2], const float* __restrict__ bias,
    float* __restrict__ p, int b, int oc0, int nq, int r, int kq) {
#pragma unroll
    for (int j = 0; j < 2; ++j) {
        int oc = oc0 + (nq * 2 + j) * 16 + r;
        float bv = bias[oc];
#pragma unroll
        for (int i = 0; i < NMF; ++i) {
            int row = b * 144 + (MF0 + i) * 16 + kq * 4;
#pragma unroll
            for (int reg = 0; reg < 4; ++reg)
                p[(size_t)(row + reg) * 256 + oc] = acc[i][j][reg] + bv;
        }
    }
}

__global__ __launch_bounds__(512)
__attribute__((amdgpu_waves_per_eu(2, 2)))
void k_conv2s(
    const ushort* __restrict__ x1h, const ushort* __restrict__ x1l,
    const ushort* __restrict__ bpk,
    const float* __restrict__ bias, float* __restrict__ p) {
    __shared__ __align__(16) ushort A_lds[32000];  // [comp 2][cell 400][pitch 40]
    __shared__ __align__(16) ushort Bb[49152];     // [buf 6][comp 2][kq 4][ocl 128][8]

    const int tid = threadIdx.x;
    const int lane = tid & 63;
    const int wv = tid >> 6;          // 0..7
    const int mh = wv >> 2;           // 0..1 (M split: frag tiles 0-4 / 5-8)
    const int nq = wv & 3;            // 0..3 (N split: 2 oc-tiles of 16 each)
    const int b  = blockIdx.x >> 1;
    const int nt = blockIdx.x & 1;
    const int oc0 = nt * 128;
    const int r = lane & 15, kq = lane >> 4;
    const int MF0r = mh ? 5 : 0;

    int celloff[5];
#pragma unroll
    for (int i = 0; i < 5; ++i) {
        int lm = (MF0r + i) * 16 + r;
        celloff[i] = ((lm / 12) * 20 + (lm % 12)) * 40 + kq * 8;
    }
    // B frag LDS offsets (ushorts, within comp plane)
    const int bro0 = kq * 1024 + ((nq * 2 + 0) * 16 + r) * 8;
    const int bro1 = kq * 1024 + ((nq * 2 + 1) * 16 + r) * 8;

    // staging assignment: wave -> (comp_w, kq_w) slice of each tap's 16KB tile
    const int comp_w = wv >> 2, kq_w = wv & 3;
    const ushort* gB0 = bpk + comp_w * 8192 + kq_w * 2048 + oc0 * 8 + lane * 8;
    ushort* lB0 = Bb + comp_w * 4096 + kq_w * 1024;

    f32x4 acc[5][2];
#pragma unroll
    for (int i = 0; i < 5; ++i)
#pragma unroll
        for (int j = 0; j < 2; ++j)
            acc[i][j] = (f32x4){0.f, 0.f, 0.f, 0.f};

    FragR fX, fY;

    for (int icc = 0; icc < 8; ++icc) {
        const size_t gicc = (size_t)icc * 16384;
        // ---- stage A slab (previous icc's final barrier protects slab) ----
#pragma unroll
        for (int rd = 0; rd < 7; ++rd) {
            int idx = rd * 512 + tid;
            if (idx < 3200) {
                int comp = (idx >= 1600) ? 1 : 0;
                int ci = idx - comp * 1600;
                int cell = ci >> 2, cc = ci & 3;
                const ushort* src = (comp ? x1l : x1h) +
                    ((size_t)b * 400 + cell) * 256 + icc * 32 + cc * 8;
                short8 val = *(const short8*)src;
                *(short8*)(A_lds + comp * 16000 + cell * 40 + cc * 8) = val;
            }
        }
        // ---- B prologue: stage taps 0..3 into ring slots 0..3 ----
        stage_tap(gB0, lB0, 0, gicc);
        stage_tap(gB0, lB0, 1, gicc);
        stage_tap(gB0, lB0, 2, gicc);
        stage_tap(gB0, lB0, 3, gicc);
        __syncthreads();   // A + B(t0..t3) ready
        // preload first two taps into registers (exposed once per icc)
        if (mh == 0) {
            pre_fragR<5>(fX, A_lds, Bb, 0, celloff, bro0, bro1);
            pre_fragR<5>(fY, A_lds, Bb, 1, celloff, bro0, bro1);
        } else {
            pre_fragR<4>(fX, A_lds, Bb, 0, celloff, bro0, bro1);
            pre_fragR<4>(fY, A_lds, Bb, 1, celloff, bro0, bro1);
        }

        // ---- 39 phases: mfma taps T,T+1 from regs; preread T+2,T+3 ----
#pragma unroll 1
        for (int ph = 0; ph < 39; ++ph) {
            const int T = ph * 2;
            stage_tap(gB0, lB0, T + 4, gicc);
            stage_tap(gB0, lB0, T + 5, gicc);
            if (mh == 0) {
                mfma_fragR<5>(acc, fX);
                mfma_fragR<5>(acc, fY);
                pre_fragR<5>(fX, A_lds, Bb, T + 2, celloff, bro0, bro1);
                pre_fragR<5>(fY, A_lds, Bb, T + 3, celloff, bro0, bro1);
            } else {
                mfma_fragR<4>(acc, fX);
                mfma_fragR<4>(acc, fY);
                pre_fragR<4>(fX, A_lds, Bb, T + 2, celloff, bro0, bro1);
                pre_fragR<4>(fY, A_lds, Bb, T + 3, celloff, bro0, bro1);
            }
            __syncthreads();
        }
        // ---- tail: taps 78,79 from regs; preread + compute tap 80 ----
        if (mh == 0) {
            mfma_fragR<5>(acc, fX);
            mfma_fragR<5>(acc, fY);
            pre_fragR<5>(fX, A_lds, Bb, 80, celloff, bro0, bro1);
            mfma_fragR<5>(acc, fX);
        } else {
            mfma_fragR<4>(acc, fX);
            mfma_fragR<4>(acc, fY);
            pre_fragR<4>(fX, A_lds, Bb, 80, celloff, bro0, bro1);
            mfma_fragR<4>(acc, fX);
        }
        __syncthreads();   // all reads of A slab + ring done before restage
    }

    if (mh == 0) conv2s_epi<0, 5>(acc, bias, p, b, oc0, nq, r, kq);
    else         conv2s_epi<5, 4>(acc, bias, p, b, oc0, nq, r, kq);
}

// squash primary caps: p[(b*144+pos)][oc=i*32+m] -> u[b, n=m*144+pos, i]
__global__ __launch_bounds__(256) void k_squash(const float* __restrict__ p,
                                                float* __restrict__ u) {
    int id = blockIdx.x * 256 + threadIdx.x;   // B*4608
    int n = id % NCAP;
    int b = id / NCAP;
    int m = n / NPRIM, pos = n - m * NPRIM;
    const float* pp = p + ((size_t)b * 144 + pos) * 256 + m;
    float pv[8];
    float s2 = 0.f;
#pragma unroll
    for (int i = 0; i < 8; ++i) {
        pv[i] = pp[i * 32];
        s2 = fmaf(pv[i], pv[i], s2);
    }
    float f = (s2 / (1.f + s2)) / sqrtf(s2 + 1e-8f);
    float4 a = make_float4(f * pv[0], f * pv[1], f * pv[2], f * pv[3]);
    float4 c = make_float4(f * pv[4], f * pv[5], f * pv[6], f * pv[7]);
    float4* up = (float4*)(u + (size_t)id * 8);
    up[0] = a;
    up[1] = c;
}

// transpose routing weights: Wd[n][c][o][i] -> Wtv[c][o][n][i]  (i contiguous!)
// R13 post-mortem: route5 is VMEM-ISSUE bound (128 scalar dword Wt loads per
// thread per j; 32KB/wave Wt slice thrashes L1). i-innermost layout lets each
// thread read its 8 weights as 2 float4 (lane n, n+1 are 32B apart -> wave
// covers 2KB dense). 128 dword -> 32 dwordx4 per j = 4x fewer VMEM issues,
// same bytes, same FMA order.
__global__ __launch_bounds__(256) void k_prep_wt(const float* __restrict__ Wd,
                                                 float* __restrict__ Wtv) {
    __shared__ float S[64][129];
    int c = blockIdx.x % NCLS;
    int nt = blockIdx.x / NCLS;    // 0..71
    int n0 = nt * 64;
    int tid = threadIdx.x;
#pragma unroll
    for (int rep = 0; rep < 32; ++rep) {
        int idx = rep * 256 + tid;
        int nl = idx >> 7, oi = idx & 127;
        S[nl][oi] = Wd[(size_t)(n0 + nl) * 1280 + c * 128 + oi];
    }
    __syncthreads();
    // write Wtv[c][o][n][i]: 16 o x 64 nl items, 32B each (coalesced 2KB/wave)
#pragma unroll
    for (int rep = 0; rep < 4; ++rep) {
        int idx = rep * 256 + tid;
        int o = idx >> 6, nl = idx & 63;
        float4* d4 = (float4*)(Wtv + (((size_t)c * 16 + o) * NCAP + n0 + nl) * 8);
        d4[0] = make_float4(S[nl][o * 8 + 0], S[nl][o * 8 + 1],
                            S[nl][o * 8 + 2], S[nl][o * 8 + 3]);
        d4[1] = make_float4(S[nl][o * 8 + 4], S[nl][o * 8 + 5],
                            S[nl][o * 8 + 6], S[nl][o * 8 + 7]);
    }
}

// routing (R11 nb=2 structure) + XCD class-affinity swizzle (kept: cuts L2
// fills 696->434MB) + VECTORIZED Wtv[c][o][n][i] float4 weight loads.
// Math/FMA order identical to route5 -> bit-identical output.
__global__ __launch_bounds__(256) void k_route5(const float* __restrict__ u,
                                                const float* __restrict__ Wtv,
                                                float* __restrict__ v_out) {
    __shared__ float part[4][2][17];
    __shared__ float sums[2][17];
    __shared__ float vsh[2][16];
    int id = blockIdx.x;
    int c, bg;
    if (id < 512) { c = id & 7; bg = id >> 3; }          // classes 0..7: one XCD each
    else { int rr = id - 512; c = 8 + (rr >> 6); bg = rr & 63; }  // classes 8,9
    int b0 = bg * 2;
    int tid = threadIdx.x;
    int lane = tid & 63, wvi = tid >> 6;
    const float* WtC = Wtv + (size_t)c * 16 * NCAP * 8;

    float bij[18][2];
#pragma unroll
    for (int j = 0; j < 18; ++j) { bij[j][0] = 0.f; bij[j][1] = 0.f; }

    for (int iter = 0; iter < 3; ++iter) {
        float sZ[2] = {0.f, 0.f};
        float sS[2][16];
#pragma unroll
        for (int o = 0; o < 16; ++o) { sS[0][o] = 0.f; sS[1][o] = 0.f; }

        for (int j = 0; j < 18; ++j) {
            int n = j * 256 + tid;
            const float4* up0 = (const float4*)(u + ((size_t)b0 * NCAP + n) * 8);
            const float4* up1 = (const float4*)(u + ((size_t)(b0 + 1) * NCAP + n) * 8);
            float4 a0 = up0[0], a1 = up0[1];
            float4 c0 = up1[0], c1 = up1[1];
            float u0[8] = {a0.x, a0.y, a0.z, a0.w, a1.x, a1.y, a1.z, a1.w};
            float u1[8] = {c0.x, c0.y, c0.z, c0.w, c1.x, c1.y, c1.z, c1.w};
            float uh[2][16];
#pragma unroll
            for (int o = 0; o < 16; ++o) {
                const float4* wp = (const float4*)(WtC + ((size_t)o * NCAP + n) * 8);
                float4 w0 = wp[0], w1 = wp[1];
                float w[8] = {w0.x, w0.y, w0.z, w0.w, w1.x, w1.y, w1.z, w1.w};
                float s0 = 0.f, s1 = 0.f;
#pragma unroll
                for (int i = 0; i < 8; ++i) {
                    s0 = fmaf(w[i], u0[i], s0);
                    s1 = fmaf(w[i], u1[i], s1);
                }
                uh[0][o] = s0;
                uh[1][o] = s1;
            }
#pragma unroll
            for (int bb = 0; bb < 2; ++bb) {
                float e;
                if (iter == 0) {
                    e = 1.f;
                } else {
                    float agr = 0.f;
#pragma unroll
                    for (int o = 0; o < 16; ++o) agr = fmaf(uh[bb][o], vsh[bb][o], agr);
                    bij[j][bb] += agr;
                    e = __expf(bij[j][bb]);
                }
                sZ[bb] += e;
#pragma unroll
                for (int o = 0; o < 16; ++o) sS[bb][o] = fmaf(e, uh[bb][o], sS[bb][o]);
            }
        }

#pragma unroll
        for (int bb = 0; bb < 2; ++bb) {
            float z = sZ[bb];
#pragma unroll
            for (int d = 32; d >= 1; d >>= 1) z += __shfl_xor(z, d, 64);
            if (lane == 0) part[wvi][bb][0] = z;
#pragma unroll
            for (int o = 0; o < 16; ++o) {
                float s = sS[bb][o];
#pragma unroll
                for (int d = 32; d >= 1; d >>= 1) s += __shfl_xor(s, d, 64);
                if (lane == 0) part[wvi][bb][1 + o] = s;
            }
        }
        __syncthreads();
        if (tid < 34) {
            int bb = tid / 17, k = tid % 17;
            float s = 0.f;
#pragma unroll
            for (int w4 = 0; w4 < 4; ++w4) s += part[w4][bb][k];
            sums[bb][k] = s;
        }
        __syncthreads();
        if (tid < 2) {
            float Z = sums[tid][0];
            float s[16];
            float s2 = 0.f;
#pragma unroll
            for (int o = 0; o < 16; ++o) {
                s[o] = sums[tid][1 + o] / Z;
                s2 = fmaf(s[o], s[o], s2);
            }
            float f = (s2 / (1.f + s2)) / sqrtf(s2 + 1e-8f);
#pragma unroll
            for (int o = 0; o < 16; ++o) vsh[tid][o] = f * s[o];
        }
        __syncthreads();
    }
    if (tid < 32) {
        int bb = tid >> 4, o = tid & 15;
        v_out[((size_t)(b0 + bb) * NCLS + c) * 16 + o] = vsh[bb][o];
    }
}

// head: v_length, argmax, one-hot
__global__ __launch_bounds__(64) void k_head(const float* __restrict__ v,
                                             float* __restrict__ out,
                                             int* __restrict__ cls_ws) {
    __shared__ float len2[NCLS];
    __shared__ int cls_sh;
    int b = blockIdx.x, tid = threadIdx.x;
    if (tid < NCLS) {
        float s2 = 0.f;
#pragma unroll
        for (int o = 0; o < 16; ++o) {
            float t = v[((size_t)b * NCLS + tid) * 16 + o];
            s2 = fmaf(t, t, s2);
        }
        len2[tid] = s2;
        out[OUT_LEN + b * NCLS + tid] = sqrtf(s2);
    }
    __syncthreads();
    if (tid == 0) {
        int best = 0;
        float bv = len2[0];
        for (int c2 = 1; c2 < NCLS; ++c2)
            if (len2[c2] > bv) { bv = len2[c2]; best = c2; }
        cls_sh = best;
        cls_ws[b] = best;
    }
    __syncthreads();
    if (tid < NCLS) out[b * NCLS + tid] = (tid == cls_sh) ? 1.0f : 0.0f;
}

// decoder layer 1
__global__ __launch_bounds__(256) void k_dec1(const float* __restrict__ v,
                                              const int* __restrict__ cls_ws,
                                              const float* __restrict__ w1,
                                              const float* __restrict__ b1,
                                              float* __restrict__ h1) {
    int id = blockIdx.x * 256 + threadIdx.x;  // B*512
    int j = id % 512, b = id / 512;
    int cls = cls_ws[b];
    const float* vp = v + ((size_t)b * NCLS + cls) * 16;
    float acc = b1[j];
#pragma unroll
    for (int o = 0; o < 16; ++o)
        acc = fmaf(vp[o], w1[(size_t)(cls * 16 + o) * 512 + j], acc);
    h1[id] = fmaxf(acc, 0.f);
}

// decoder layer 2
__global__ __launch_bounds__(256) void k_dec2(const float* __restrict__ h1,
                                              const float* __restrict__ w2,
                                              const float* __restrict__ b2,
                                              float* __restrict__ h2) {
    __shared__ float hs[512];
    int bi = blockIdx.x;
    int jc = bi % 4;
    int b = bi / 4;
    int tid = threadIdx.x;
    hs[tid] = h1[b * 512 + tid];
    hs[tid + 256] = h1[b * 512 + tid + 256];
    __syncthreads();
    int j = jc * 256 + tid;
    float acc = b2[j];
#pragma unroll 8
    for (int k = 0; k < 512; ++k)
        acc = fmaf(hs[k], w2[(size_t)k * 1024 + j], acc);
    h2[b * 1024 + j] = fmaxf(acc, 0.f);
}

// decoder layer 3 + sigmoid
__global__ __launch_bounds__(256) void k_dec3(const float* __restrict__ h2,
                                              const float* __restrict__ w3,
                                              const float* __restrict__ b3,
                                              float* __restrict__ out) {
    __shared__ float hs[1024];
    int bi = blockIdx.x;
    int jc = bi % 4;
    int b = bi / 4;
    int tid = threadIdx.x;
#pragma unroll
    for (int t = 0; t < 4; ++t) hs[tid + t * 256] = h2[b * 1024 + tid + t * 256];
    __syncthreads();
    int j = jc * 256 + tid;
    if (j < 784) {
        float acc = b3[j];
#pragma unroll 8
        for (int k = 0; k < 1024; ++k)
            acc = fmaf(hs[k], w3[(size_t)k * 784 + j], acc);
        out[OUT_REC + b * 784 + j] = 1.f / (1.f + __expf(-acc));
    }
}

// ---------------- launcher ----------------
extern "C" void kernel_launch(void* const* d_in, const int* in_sizes, int n_in,
                              void* d_out, int out_size, void* d_ws, size_t ws_size,
                              hipStream_t stream) {
    const float* imgs = (const float*)d_in[0];
    const float* c1w  = (const float*)d_in[1];
    const float* c1b  = (const float*)d_in[2];
    const float* c2w  = (const float*)d_in[3];
    const float* c2b  = (const float*)d_in[4];
    const float* Wd   = (const float*)d_in[5];
    const float* dw1  = (const float*)d_in[6];
    const float* db1  = (const float*)d_in[7];
    const float* dw2  = (const float*)d_in[8];
    const float* db2  = (const float*)d_in[9];
    const float* dw3  = (const float*)d_in[10];
    const float* db3  = (const float*)d_in[11];

    float* out = (float*)d_out;
    float* ws  = (float*)d_ws;
    ushort* x1h = (ushort*)(ws + WS_X1H);
    ushort* x1l = (ushort*)(ws + WS_X1L);
    ushort* bpk = (ushort*)(ws + WS_BH);   // 81*131072 ushorts = 21.23 MB
    float* p    = ws + WS_P;
    float* u    = ws + WS_U;
    float* v    = ws + WS_V;
    float* h1   = ws + WS_H1;
    float* h2   = ws + WS_H2;
    int*   cls  = (int*)(ws + WS_CLS);
    float* wtv  = ws + WS_X1H;   // reuses x1h region (dead after k_conv2s)

    k_conv1<<<BB * 20, 256, 0, stream>>>(imgs, c1w, c1b, x1h, x1l);
    k_prep_w2<<<256, 256, 0, stream>>>(c2w, bpk);
    k_conv2s<<<BB * 2, 512, 0, stream>>>(x1h, x1l, bpk, c2b, p);
    k_squash<<<BB * NCAP / 256, 256, 0, stream>>>(p, u);
    k_prep_wt<<<720, 256, 0, stream>>>(Wd, wtv);   // after conv2s: x1h region now free
    k_route5<<<(BB / 2) * NCLS, 256, 0, stream>>>(u, wtv, v);
    k_head<<<BB, 64, 0, stream>>>(v, out, cls);
    k_dec1<<<BB * 512 / 256, 256, 0, stream>>>(v, cls, dw1, db1, h1);
    k_dec2<<<BB * 4, 256, 0, stream>>>(h1, dw2, db2, h2);
    k_dec3<<<BB * 4, 256, 0, stream>>>(h2, dw3, db3, out);
}

// Round 15
// 1123.563 us; speedup vs baseline: 1.0176x; 1.0176x over previous
//
#include <hip/hip_runtime.h>
#include <cstdint>
#include <cstddef>

// ---------------- problem constants ----------------
#define BB 128
#define NMAP 32
#define NPRIM 144
#define NCAP 4608      // 32*144
#define NCLS 10
#define ODIM 16
#define IDIM 8

// ws layout (float offsets)
#define WS_X1H  0                       // x1 hi bf16 NHWC ushort; later reused for Wtv fp32 (5.9M fl)
#define WS_X1L  6553600                 // x1 lo bf16
#define WS_BH   13107200                // packed conv2 weights Bpk: [81 t][8 icc][2 comp][4 kq][256 oc][8] ushort
#define WS_P    18415616                // conv2 out NHWC: [128*144][256]
#define WS_U    23134208                // squash:   [128][4608][8]
#define WS_V    27852800                // routing v: [128][10][16]
#define WS_H1   27873280                // dec h1: [128][512]
#define WS_H2   27938816                // dec h2: [128][1024]
#define WS_CLS  28069888                // argmax class per b (int), 128

// out layout (floats): [128*10 onehot][128*784 reconst][128*10 v_length]
#define OUT_REC  1280
#define OUT_LEN  101632

typedef __attribute__((ext_vector_type(8))) short short8;
typedef __attribute__((ext_vector_type(4))) float f32x4;

// round-to-nearest-even fp32 -> bf16 bits
static __device__ __forceinline__ ushort f2bf(float f) {
    uint u = __float_as_uint(f);
    u = (u + 0x7FFFu + ((u >> 16) & 1u)) >> 16;
    return (ushort)u;
}
static __device__ __forceinline__ float bf2f(ushort h) {
    return __uint_as_float(((uint)h) << 16);
}

// async global->LDS, 16B per lane. Global addr is PER-LANE; LDS dest is
// wave-uniform base + lane*16 (HW-added).
static __device__ __forceinline__ void gload16(const ushort* g, ushort* l) {
    __builtin_amdgcn_global_load_lds(
        (const __attribute__((address_space(1))) void*)g,
        (__attribute__((address_space(3))) void*)l, 16, 0, 0);
}

// ---------------- kernels ----------------

// conv1 + bias + relu, emitting NHWC bf16 hi/lo directly.
__global__ __launch_bounds__(256) void k_conv1(const float* __restrict__ img,
                                               const float* __restrict__ w,
                                               const float* __restrict__ bias,
                                               ushort* __restrict__ x1h,
                                               ushort* __restrict__ x1l) {
    __shared__ float simg[252];   // 9 rows x 28 cols
    int bi = blockIdx.x;
    int y = bi % 20;
    int b = bi / 20;
    int oc = threadIdx.x;
    if (threadIdx.x < 252)
        simg[threadIdx.x] = img[(size_t)b * 784 + y * 28 + threadIdx.x];
    __syncthreads();

    float acc[20];
    float bv = bias[oc];
#pragma unroll
    for (int x = 0; x < 20; ++x) acc[x] = bv;
    const float* wp = w + oc * 81;
#pragma unroll
    for (int kh = 0; kh < 9; ++kh) {
        float r[28];
#pragma unroll
        for (int j = 0; j < 28; ++j) r[j] = simg[kh * 28 + j];
#pragma unroll
        for (int kw = 0; kw < 9; ++kw) {
            float wv = wp[kh * 9 + kw];
#pragma unroll
            for (int x = 0; x < 20; ++x)
                acc[x] = fmaf(wv, r[x + kw], acc[x]);
        }
    }
    size_t base = ((size_t)b * 400 + y * 20) * 256 + oc;
#pragma unroll
    for (int x = 0; x < 20; ++x) {
        float v = fmaxf(acc[x], 0.f);
        ushort h = f2bf(v);
        ushort lo = f2bf(v - bf2f(h));
        x1h[base + (size_t)x * 256] = h;
        x1l[base + (size_t)x * 256] = lo;
    }
}

// conv2 weights repack for LDS staging:
// w2[oc][ic][81] fp32 -> Bpk[t][icc][comp][kq][oc 256][ic8 8] bf16 hi/lo.
__global__ __launch_bounds__(256) void k_prep_w2(const float* __restrict__ w2,
                                                 ushort* __restrict__ bpk) {
    int blk = blockIdx.x;            // 256 = icc*32 + kq*8 + ocg
    int icc = blk >> 5, kq = (blk >> 3) & 3, ocg = blk & 7;
    int tid = threadIdx.x;
    int ocl = tid >> 3, ic8 = tid & 7;
    int oc = ocg * 32 + ocl;
    int ic = icc * 32 + kq * 8 + ic8;
    const float* src = w2 + ((size_t)oc * 256 + ic) * 81;
    size_t dbase = (size_t)icc * 16384 + (size_t)kq * 2048 + (size_t)oc * 8 + ic8;
#pragma unroll 9
    for (int t = 0; t < 81; ++t) {
        float v = src[t];
        ushort h = f2bf(v);
        ushort lo = f2bf(v - bf2f(h));
        bpk[(size_t)t * 131072 + dbase] = h;            // comp 0 (hi)
        bpk[(size_t)t * 131072 + dbase + 8192] = lo;    // comp 1 (lo)
    }
}

// ---- conv2: A slab + 6-deep async B ring + cross-phase REGISTER pipeline ----
// R11 verdict: 533us, MfmaUtil 49%. Three scheduling attacks all land
// 533-564 -> HIP-source ceiling for this barrier structure. FROZEN.
static __device__ __forceinline__ f32x4 mfma16(short8 a, short8 b, f32x4 c) {
    return __builtin_amdgcn_mfma_f32_16x16x32_bf16(a, b, c, 0, 0, 0);
}

struct FragR { short8 ah[5], al[5], bh0, bh1, bl0, bl1; };

template<int NMF>
static __device__ __forceinline__ void pre_fragR(
    FragR& f, const ushort* A_lds, const ushort* Bb, int tn,
    const int* celloff, int bro0, int bro1) {
    int kh = tn / 9, kw = tn - kh * 9;
    int tapoff = (kh * 20 + kw) * 40;
    const ushort* Bc = Bb + (tn % 6) * 8192;
#pragma unroll
    for (int i = 0; i < NMF; ++i) {
        f.ah[i] = *(const short8*)(A_lds + tapoff + celloff[i]);
        f.al[i] = *(const short8*)(A_lds + 16000 + tapoff + celloff[i]);
    }
    f.bh0 = *(const short8*)(Bc + bro0);
    f.bh1 = *(const short8*)(Bc + bro1);
    f.bl0 = *(const short8*)(Bc + 4096 + bro0);
    f.bl1 = *(const short8*)(Bc + 4096 + bro1);
}

template<int NMF>
static __device__ __forceinline__ void mfma_fragR(f32x4 (&acc)[5][2], const FragR& f) {
#pragma unroll
    for (int i = 0; i < NMF; ++i) {
        acc[i][0] = mfma16(f.ah[i], f.bh0, acc[i][0]);
        acc[i][1] = mfma16(f.ah[i], f.bh1, acc[i][1]);
    }
#pragma unroll
    for (int i = 0; i < NMF; ++i) {
        acc[i][0] = mfma16(f.ah[i], f.bl0, acc[i][0]);
        acc[i][1] = mfma16(f.ah[i], f.bl1, acc[i][1]);
    }
#pragma unroll
    for (int i = 0; i < NMF; ++i) {
        acc[i][0] = mfma16(f.al[i], f.bh0, acc[i][0]);
        acc[i][1] = mfma16(f.al[i], f.bh1, acc[i][1]);
    }
}

static __device__ __forceinline__ void stage_tap(
    const ushort* gB0, ushort* lB0, int tn, size_t gicc) {
    if (tn <= 80) {
        size_t g = (size_t)tn * 131072 + gicc;
        ushort* d = lB0 + (tn % 6) * 8192;
        gload16(gB0 + g, d);
        gload16(gB0 + g + 512, d + 512);
    }
}

template<int MF0, int NMF>
static __device__ __forceinline__ void conv2s_epi(
    const f32x4 (&acc)[5][2], const float* __restrict__ bias,
    float* __restrict__ p, int b, int oc0, int nq, int r, int kq) {
#pragma unroll
    for (int j = 0; j < 2; ++j) {
        int oc = oc0 + (nq * 2 + j) * 16 + r;
        float bv = bias[oc];
#pragma unroll
        for (int i = 0; i < NMF; ++i) {
            int row = b * 144 + (MF0 + i) * 16 + kq * 4;
#pragma unroll
            for (int reg = 0; reg < 4; ++reg)
                p[(size_t)(row + reg) * 256 + oc] = acc[i][j][reg] + bv;
        }
    }
}

__global__ __launch_bounds__(512)
__attribute__((amdgpu_waves_per_eu(2, 2)))
void k_conv2s(
    const ushort* __restrict__ x1h, const ushort* __restrict__ x1l,
    const ushort* __restrict__ bpk,
    const float* __restrict__ bias, float* __restrict__ p) {
    __shared__ __align__(16) ushort A_lds[32000];  // [comp 2][cell 400][pitch 40]
    __shared__ __align__(16) ushort Bb[49152];     // [buf 6][comp 2][kq 4][ocl 128][8]

    const int tid = threadIdx.x;
    const int lane = tid & 63;
    const int wv = tid >> 6;          // 0..7
    const int mh = wv >> 2;           // 0..1 (M split: frag tiles 0-4 / 5-8)
    const int nq = wv & 3;            // 0..3 (N split: 2 oc-tiles of 16 each)
    const int b  = blockIdx.x >> 1;
    const int nt = blockIdx.x & 1;
    const int oc0 = nt * 128;
    const int r = lane & 15, kq = lane >> 4;
    const int MF0r = mh ? 5 : 0;

    int celloff[5];
#pragma unroll
    for (int i = 0; i < 5; ++i) {
        int lm = (MF0r + i) * 16 + r;
        celloff[i] = ((lm / 12) * 20 + (lm % 12)) * 40 + kq * 8;
    }
    // B frag LDS offsets (ushorts, within comp plane)
    const int bro0 = kq * 1024 + ((nq * 2 + 0) * 16 + r) * 8;
    const int bro1 = kq * 1024 + ((nq * 2 + 1) * 16 + r) * 8;

    // staging assignment: wave -> (comp_w, kq_w) slice of each tap's 16KB tile
    const int comp_w = wv >> 2, kq_w = wv & 3;
    const ushort* gB0 = bpk + comp_w * 8192 + kq_w * 2048 + oc0 * 8 + lane * 8;
    ushort* lB0 = Bb + comp_w * 4096 + kq_w * 1024;

    f32x4 acc[5][2];
#pragma unroll
    for (int i = 0; i < 5; ++i)
#pragma unroll
        for (int j = 0; j < 2; ++j)
            acc[i][j] = (f32x4){0.f, 0.f, 0.f, 0.f};

    FragR fX, fY;

    for (int icc = 0; icc < 8; ++icc) {
        const size_t gicc = (size_t)icc * 16384;
        // ---- stage A slab (previous icc's final barrier protects slab) ----
#pragma unroll
        for (int rd = 0; rd < 7; ++rd) {
            int idx = rd * 512 + tid;
            if (idx < 3200) {
                int comp = (idx >= 1600) ? 1 : 0;
                int ci = idx - comp * 1600;
                int cell = ci >> 2, cc = ci & 3;
                const ushort* src = (comp ? x1l : x1h) +
                    ((size_t)b * 400 + cell) * 256 + icc * 32 + cc * 8;
                short8 val = *(const short8*)src;
                *(short8*)(A_lds + comp * 16000 + cell * 40 + cc * 8) = val;
            }
        }
        // ---- B prologue: stage taps 0..3 into ring slots 0..3 ----
        stage_tap(gB0, lB0, 0, gicc);
        stage_tap(gB0, lB0, 1, gicc);
        stage_tap(gB0, lB0, 2, gicc);
        stage_tap(gB0, lB0, 3, gicc);
        __syncthreads();   // A + B(t0..t3) ready
        // preload first two taps into registers (exposed once per icc)
        if (mh == 0) {
            pre_fragR<5>(fX, A_lds, Bb, 0, celloff, bro0, bro1);
            pre_fragR<5>(fY, A_lds, Bb, 1, celloff, bro0, bro1);
        } else {
            pre_fragR<4>(fX, A_lds, Bb, 0, celloff, bro0, bro1);
            pre_fragR<4>(fY, A_lds, Bb, 1, celloff, bro0, bro1);
        }

        // ---- 39 phases: mfma taps T,T+1 from regs; preread T+2,T+3 ----
#pragma unroll 1
        for (int ph = 0; ph < 39; ++ph) {
            const int T = ph * 2;
            stage_tap(gB0, lB0, T + 4, gicc);
            stage_tap(gB0, lB0, T + 5, gicc);
            if (mh == 0) {
                mfma_fragR<5>(acc, fX);
                mfma_fragR<5>(acc, fY);
                pre_fragR<5>(fX, A_lds, Bb, T + 2, celloff, bro0, bro1);
                pre_fragR<5>(fY, A_lds, Bb, T + 3, celloff, bro0, bro1);
            } else {
                mfma_fragR<4>(acc, fX);
                mfma_fragR<4>(acc, fY);
                pre_fragR<4>(fX, A_lds, Bb, T + 2, celloff, bro0, bro1);
                pre_fragR<4>(fY, A_lds, Bb, T + 3, celloff, bro0, bro1);
            }
            __syncthreads();
        }
        // ---- tail: taps 78,79 from regs; preread + compute tap 80 ----
        if (mh == 0) {
            mfma_fragR<5>(acc, fX);
            mfma_fragR<5>(acc, fY);
            pre_fragR<5>(fX, A_lds, Bb, 80, celloff, bro0, bro1);
            mfma_fragR<5>(acc, fX);
        } else {
            mfma_fragR<4>(acc, fX);
            mfma_fragR<4>(acc, fY);
            pre_fragR<4>(fX, A_lds, Bb, 80, celloff, bro0, bro1);
            mfma_fragR<4>(acc, fX);
        }
        __syncthreads();   // all reads of A slab + ring done before restage
    }

    if (mh == 0) conv2s_epi<0, 5>(acc, bias, p, b, oc0, nq, r, kq);
    else         conv2s_epi<5, 4>(acc, bias, p, b, oc0, nq, r, kq);
}

// squash v2: COALESCED p reads via LDS tile. Old version gathered
// p[(b*144+pos)*256 + m + i*32] at 1KB lane stride (6% line density, 16x
// L2->L1 amplification, latency-exposed). Now: 8 p-rows per block staged as
// dense 1KB wave-loads into S[8][256]; LDS re-read is 2-way-conflict (free);
// writes become 32B-scattered but stores don't stall. Same per-capsule
// values and FMA order -> bit-identical u. Grid unchanged (2304 x 256).
__global__ __launch_bounds__(256) void k_squash(const float* __restrict__ p,
                                                float* __restrict__ u) {
    __shared__ float S[2048];          // [8 rows][256 oc]
    const int tid = threadIdx.x;
    const int r0 = blockIdx.x * 8;     // global row = b*144 + pos; 144%8==0
    const int b = blockIdx.x / 18;     // 18 blocks per batch image
    const int pos0 = (blockIdx.x % 18) * 8;
#pragma unroll
    for (int k = 0; k < 8; ++k)
        S[k * 256 + tid] = p[(size_t)(r0 + k) * 256 + tid];
    __syncthreads();
    const int r = tid >> 5, m = tid & 31;
    float pv[8];
    float s2 = 0.f;
#pragma unroll
    for (int i = 0; i < 8; ++i) {
        pv[i] = S[r * 256 + i * 32 + m];
        s2 = fmaf(pv[i], pv[i], s2);
    }
    float f = (s2 / (1.f + s2)) / sqrtf(s2 + 1e-8f);
    size_t n = (size_t)b * NCAP + m * NPRIM + (pos0 + r);
    float4* up = (float4*)(u + n * 8);
    up[0] = make_float4(f * pv[0], f * pv[1], f * pv[2], f * pv[3]);
    up[1] = make_float4(f * pv[4], f * pv[5], f * pv[6], f * pv[7]);
}

// transpose routing weights: Wd[n][c][o][i] -> Wtv[c][o][n][i]  (i contiguous)
__global__ __launch_bounds__(256) void k_prep_wt(const float* __restrict__ Wd,
                                                 float* __restrict__ Wtv) {
    __shared__ float S[64][129];
    int c = blockIdx.x % NCLS;
    int nt = blockIdx.x / NCLS;    // 0..71
    int n0 = nt * 64;
    int tid = threadIdx.x;
#pragma unroll
    for (int rep = 0; rep < 32; ++rep) {
        int idx = rep * 256 + tid;
        int nl = idx >> 7, oi = idx & 127;
        S[nl][oi] = Wd[(size_t)(n0 + nl) * 1280 + c * 128 + oi];
    }
    __syncthreads();
    // write Wtv[c][o][n][i]: 16 o x 64 nl items, 32B each (coalesced 2KB/wave)
#pragma unroll
    for (int rep = 0; rep < 4; ++rep) {
        int idx = rep * 256 + tid;
        int o = idx >> 6, nl = idx & 63;
        float4* d4 = (float4*)(Wtv + (((size_t)c * 16 + o) * NCAP + n0 + nl) * 8);
        d4[0] = make_float4(S[nl][o * 8 + 0], S[nl][o * 8 + 1],
                            S[nl][o * 8 + 2], S[nl][o * 8 + 3]);
        d4[1] = make_float4(S[nl][o * 8 + 4], S[nl][o * 8 + 5],
                            S[nl][o * 8 + 6], S[nl][o * 8 + 7]);
    }
}

// routing (R11 nb=2 structure) + XCD class-affinity swizzle + vectorized Wtv.
// R13/R14 verdict: neither fill-BW nor VMEM-issue bound; both fixes null.
// FROZEN pending new counter evidence.
__global__ __launch_bounds__(256) void k_route5(const float* __restrict__ u,
                                                const float* __restrict__ Wtv,
                                                float* __restrict__ v_out) {
    __shared__ float part[4][2][17];
    __shared__ float sums[2][17];
    __shared__ float vsh[2][16];
    int id = blockIdx.x;
    int c, bg;
    if (id < 512) { c = id & 7; bg = id >> 3; }          // classes 0..7: one XCD each
    else { int rr = id - 512; c = 8 + (rr >> 6); bg = rr & 63; }  // classes 8,9
    int b0 = bg * 2;
    int tid = threadIdx.x;
    int lane = tid & 63, wvi = tid >> 6;
    const float* WtC = Wtv + (size_t)c * 16 * NCAP * 8;

    float bij[18][2];
#pragma unroll
    for (int j = 0; j < 18; ++j) { bij[j][0] = 0.f; bij[j][1] = 0.f; }

    for (int iter = 0; iter < 3; ++iter) {
        float sZ[2] = {0.f, 0.f};
        float sS[2][16];
#pragma unroll
        for (int o = 0; o < 16; ++o) { sS[0][o] = 0.f; sS[1][o] = 0.f; }

        for (int j = 0; j < 18; ++j) {
            int n = j * 256 + tid;
            const float4* up0 = (const float4*)(u + ((size_t)b0 * NCAP + n) * 8);
            const float4* up1 = (const float4*)(u + ((size_t)(b0 + 1) * NCAP + n) * 8);
            float4 a0 = up0[0], a1 = up0[1];
            float4 c0 = up1[0], c1 = up1[1];
            float u0[8] = {a0.x, a0.y, a0.z, a0.w, a1.x, a1.y, a1.z, a1.w};
            float u1[8] = {c0.x, c0.y, c0.z, c0.w, c1.x, c1.y, c1.z, c1.w};
            float uh[2][16];
#pragma unroll
            for (int o = 0; o < 16; ++o) {
                const float4* wp = (const float4*)(WtC + ((size_t)o * NCAP + n) * 8);
                float4 w0 = wp[0], w1 = wp[1];
                float w[8] = {w0.x, w0.y, w0.z, w0.w, w1.x, w1.y, w1.z, w1.w};
                float s0 = 0.f, s1 = 0.f;
#pragma unroll
                for (int i = 0; i < 8; ++i) {
                    s0 = fmaf(w[i], u0[i], s0);
                    s1 = fmaf(w[i], u1[i], s1);
                }
                uh[0][o] = s0;
                uh[1][o] = s1;
            }
#pragma unroll
            for (int bb = 0; bb < 2; ++bb) {
                float e;
                if (iter == 0) {
                    e = 1.f;
                } else {
                    float agr = 0.f;
#pragma unroll
                    for (int o = 0; o < 16; ++o) agr = fmaf(uh[bb][o], vsh[bb][o], agr);
                    bij[j][bb] += agr;
                    e = __expf(bij[j][bb]);
                }
                sZ[bb] += e;
#pragma unroll
                for (int o = 0; o < 16; ++o) sS[bb][o] = fmaf(e, uh[bb][o], sS[bb][o]);
            }
        }

#pragma unroll
        for (int bb = 0; bb < 2; ++bb) {
            float z = sZ[bb];
#pragma unroll
            for (int d = 32; d >= 1; d >>= 1) z += __shfl_xor(z, d, 64);
            if (lane == 0) part[wvi][bb][0] = z;
#pragma unroll
            for (int o = 0; o < 16; ++o) {
                float s = sS[bb][o];
#pragma unroll
                for (int d = 32; d >= 1; d >>= 1) s += __shfl_xor(s, d, 64);
                if (lane == 0) part[wvi][bb][1 + o] = s;
            }
        }
        __syncthreads();
        if (tid < 34) {
            int bb = tid / 17, k = tid % 17;
            float s = 0.f;
#pragma unroll
            for (int w4 = 0; w4 < 4; ++w4) s += part[w4][bb][k];
            sums[bb][k] = s;
        }
        __syncthreads();
        if (tid < 2) {
            float Z = sums[tid][0];
            float s[16];
            float s2 = 0.f;
#pragma unroll
            for (int o = 0; o < 16; ++o) {
                s[o] = sums[tid][1 + o] / Z;
                s2 = fmaf(s[o], s[o], s2);
            }
            float f = (s2 / (1.f + s2)) / sqrtf(s2 + 1e-8f);
#pragma unroll
            for (int o = 0; o < 16; ++o) vsh[tid][o] = f * s[o];
        }
        __syncthreads();
    }
    if (tid < 32) {
        int bb = tid >> 4, o = tid & 15;
        v_out[((size_t)(b0 + bb) * NCLS + c) * 16 + o] = vsh[bb][o];
    }
}

// head: v_length, argmax, one-hot
__global__ __launch_bounds__(64) void k_head(const float* __restrict__ v,
                                             float* __restrict__ out,
                                             int* __restrict__ cls_ws) {
    __shared__ float len2[NCLS];
    __shared__ int cls_sh;
    int b = blockIdx.x, tid = threadIdx.x;
    if (tid < NCLS) {
        float s2 = 0.f;
#pragma unroll
        for (int o = 0; o < 16; ++o) {
            float t = v[((size_t)b * NCLS + tid) * 16 + o];
            s2 = fmaf(t, t, s2);
        }
        len2[tid] = s2;
        out[OUT_LEN + b * NCLS + tid] = sqrtf(s2);
    }
    __syncthreads();
    if (tid == 0) {
        int best = 0;
        float bv = len2[0];
        for (int c2 = 1; c2 < NCLS; ++c2)
            if (len2[c2] > bv) { bv = len2[c2]; best = c2; }
        cls_sh = best;
        cls_ws[b] = best;
    }
    __syncthreads();
    if (tid < NCLS) out[b * NCLS + tid] = (tid == cls_sh) ? 1.0f : 0.0f;
}

// decoder layer 1
__global__ __launch_bounds__(256) void k_dec1(const float* __restrict__ v,
                                              const int* __restrict__ cls_ws,
                                              const float* __restrict__ w1,
                                              const float* __restrict__ b1,
                                              float* __restrict__ h1) {
    int id = blockIdx.x * 256 + threadIdx.x;  // B*512
    int j = id % 512, b = id / 512;
    int cls = cls_ws[b];
    const float* vp = v + ((size_t)b * NCLS + cls) * 16;
    float acc = b1[j];
#pragma unroll
    for (int o = 0; o < 16; ++o)
        acc = fmaf(vp[o], w1[(size_t)(cls * 16 + o) * 512 + j], acc);
    h1[id] = fmaxf(acc, 0.f);
}

// decoder layer 2
__global__ __launch_bounds__(256) void k_dec2(const float* __restrict__ h1,
                                              const float* __restrict__ w2,
                                              const float* __restrict__ b2,
                                              float* __restrict__ h2) {
    __shared__ float hs[512];
    int bi = blockIdx.x;
    int jc = bi % 4;
    int b = bi / 4;
    int tid = threadIdx.x;
    hs[tid] = h1[b * 512 + tid];
    hs[tid + 256] = h1[b * 512 + tid + 256];
    __syncthreads();
    int j = jc * 256 + tid;
    float acc = b2[j];
#pragma unroll 8
    for (int k = 0; k < 512; ++k)
        acc = fmaf(hs[k], w2[(size_t)k * 1024 + j], acc);
    h2[b * 1024 + j] = fmaxf(acc, 0.f);
}

// decoder layer 3 + sigmoid
__global__ __launch_bounds__(256) void k_dec3(const float* __restrict__ h2,
                                              const float* __restrict__ w3,
                                              const float* __restrict__ b3,
                                              float* __restrict__ out) {
    __shared__ float hs[1024];
    int bi = blockIdx.x;
    int jc = bi % 4;
    int b = bi / 4;
    int tid = threadIdx.x;
#pragma unroll
    for (int t = 0; t < 4; ++t) hs[tid + t * 256] = h2[b * 1024 + tid + t * 256];
    __syncthreads();
    int j = jc * 256 + tid;
    if (j < 784) {
        float acc = b3[j];
#pragma unroll 8
        for (int k = 0; k < 1024; ++k)
            acc = fmaf(hs[k], w3[(size_t)k * 784 + j], acc);
        out[OUT_REC + b * 784 + j] = 1.f / (1.f + __expf(-acc));
    }
}

// ---------------- launcher ----------------
extern "C" void kernel_launch(void* const* d_in, const int* in_sizes, int n_in,
                              void* d_out, int out_size, void* d_ws, size_t ws_size,
                              hipStream_t stream) {
    const float* imgs = (const float*)d_in[0];
    const float* c1w  = (const float*)d_in[1];
    const float* c1b  = (const float*)d_in[2];
    const float* c2w  = (const float*)d_in[3];
    const float* c2b  = (const float*)d_in[4];
    const float* Wd   = (const float*)d_in[5];
    const float* dw1  = (const float*)d_in[6];
    const float* db1  = (const float*)d_in[7];
    const float* dw2  = (const float*)d_in[8];
    const float* db2  = (const float*)d_in[9];
    const float* dw3  = (const float*)d_in[10];
    const float* db3  = (const float*)d_in[11];

    float* out = (float*)d_out;
    float* ws  = (float*)d_ws;
    ushort* x1h = (ushort*)(ws + WS_X1H);
    ushort* x1l = (ushort*)(ws + WS_X1L);
    ushort* bpk = (ushort*)(ws + WS_BH);   // 81*131072 ushorts = 21.23 MB
    float* p    = ws + WS_P;
    float* u    = ws + WS_U;
    float* v    = ws + WS_V;
    float* h1   = ws + WS_H1;
    float* h2   = ws + WS_H2;
    int*   cls  = (int*)(ws + WS_CLS);
    float* wtv  = ws + WS_X1H;   // reuses x1h region (dead after k_conv2s)

    k_conv1<<<BB * 20, 256, 0, stream>>>(imgs, c1w, c1b, x1h, x1l);
    k_prep_w2<<<256, 256, 0, stream>>>(c2w, bpk);
    k_conv2s<<<BB * 2, 512, 0, stream>>>(x1h, x1l, bpk, c2b, p);
    k_squash<<<BB * NCAP / 256, 256, 0, stream>>>(p, u);
    k_prep_wt<<<720, 256, 0, stream>>>(Wd, wtv);   // after conv2s: x1h region now free
    k_route5<<<(BB / 2) * NCLS, 256, 0, stream>>>(u, wtv, v);
    k_head<<<BB, 64, 0, stream>>>(v, out, cls);
    k_dec1<<<BB * 512 / 256, 256, 0, stream>>>(v, cls, dw1, db1, h1);
    k_dec2<<<BB * 4, 256, 0, stream>>>(h1, dw2, db2, h2);
    k_dec3<<<BB * 4, 256, 0, stream>>>(h2, dw3, db3, out);
}

// Round 16
// 1111.029 us; speedup vs baseline: 1.0291x; 1.0113x over previous
//
#include <hip/hip_runtime.h>
#include <cstdint>
#include <cstddef>

// ---------------- problem constants ----------------
#define BB 128
#define NMAP 32
#define NPRIM 144
#define NCAP 4608      // 32*144
#define NCLS 10
#define ODIM 16
#define IDIM 8

// ws layout (float offsets)
#define WS_X1H  0                       // x1 hi bf16 NHWC ushort; later reused for Wtv fp32 (5.9M fl)
#define WS_X1L  6553600                 // x1 lo bf16
#define WS_BH   13107200                // packed conv2 weights Bpk: [81 t][8 icc][2 comp][4 kq][256 oc][8] ushort
#define WS_P    18415616                // conv2 out NHWC: [128*144][256]
#define WS_U    23134208                // squash:   [128][4608][8]
#define WS_V    27852800                // routing v: [128][10][16]
#define WS_H1   27873280                // dec h1: [128][512]
#define WS_H2   27938816                // dec h2: [128][1024]
#define WS_CLS  28069888                // argmax class per b (int), 128

// out layout (floats): [128*10 onehot][128*784 reconst][128*10 v_length]
#define OUT_REC  1280
#define OUT_LEN  101632

typedef __attribute__((ext_vector_type(8))) short short8;
typedef __attribute__((ext_vector_type(4))) float f32x4;

// round-to-nearest-even fp32 -> bf16 bits
static __device__ __forceinline__ ushort f2bf(float f) {
    uint u = __float_as_uint(f);
    u = (u + 0x7FFFu + ((u >> 16) & 1u)) >> 16;
    return (ushort)u;
}
static __device__ __forceinline__ float bf2f(ushort h) {
    return __uint_as_float(((uint)h) << 16);
}

// async global->LDS, 16B per lane. Global addr is PER-LANE; LDS dest is
// wave-uniform base + lane*16 (HW-added).
static __device__ __forceinline__ void gload16(const ushort* g, ushort* l) {
    __builtin_amdgcn_global_load_lds(
        (const __attribute__((address_space(1))) void*)g,
        (__attribute__((address_space(3))) void*)l, 16, 0, 0);
}

// ---------------- kernels ----------------

// conv1 + bias + relu, emitting NHWC bf16 hi/lo directly.
__global__ __launch_bounds__(256) void k_conv1(const float* __restrict__ img,
                                               const float* __restrict__ w,
                                               const float* __restrict__ bias,
                                               ushort* __restrict__ x1h,
                                               ushort* __restrict__ x1l) {
    __shared__ float simg[252];   // 9 rows x 28 cols
    int bi = blockIdx.x;
    int y = bi % 20;
    int b = bi / 20;
    int oc = threadIdx.x;
    if (threadIdx.x < 252)
        simg[threadIdx.x] = img[(size_t)b * 784 + y * 28 + threadIdx.x];
    __syncthreads();

    float acc[20];
    float bv = bias[oc];
#pragma unroll
    for (int x = 0; x < 20; ++x) acc[x] = bv;
    const float* wp = w + oc * 81;
#pragma unroll
    for (int kh = 0; kh < 9; ++kh) {
        float r[28];
#pragma unroll
        for (int j = 0; j < 28; ++j) r[j] = simg[kh * 28 + j];
#pragma unroll
        for (int kw = 0; kw < 9; ++kw) {
            float wv = wp[kh * 9 + kw];
#pragma unroll
            for (int x = 0; x < 20; ++x)
                acc[x] = fmaf(wv, r[x + kw], acc[x]);
        }
    }
    size_t base = ((size_t)b * 400 + y * 20) * 256 + oc;
#pragma unroll
    for (int x = 0; x < 20; ++x) {
        float v = fmaxf(acc[x], 0.f);
        ushort h = f2bf(v);
        ushort lo = f2bf(v - bf2f(h));
        x1h[base + (size_t)x * 256] = h;
        x1l[base + (size_t)x * 256] = lo;
    }
}

// conv2 weights repack for LDS staging:
// w2[oc][ic][81] fp32 -> Bpk[t][icc][comp][kq][oc 256][ic8 8] bf16 hi/lo.
__global__ __launch_bounds__(256) void k_prep_w2(const float* __restrict__ w2,
                                                 ushort* __restrict__ bpk) {
    int blk = blockIdx.x;            // 256 = icc*32 + kq*8 + ocg
    int icc = blk >> 5, kq = (blk >> 3) & 3, ocg = blk & 7;
    int tid = threadIdx.x;
    int ocl = tid >> 3, ic8 = tid & 7;
    int oc = ocg * 32 + ocl;
    int ic = icc * 32 + kq * 8 + ic8;
    const float* src = w2 + ((size_t)oc * 256 + ic) * 81;
    size_t dbase = (size_t)icc * 16384 + (size_t)kq * 2048 + (size_t)oc * 8 + ic8;
#pragma unroll 9
    for (int t = 0; t < 81; ++t) {
        float v = src[t];
        ushort h = f2bf(v);
        ushort lo = f2bf(v - bf2f(h));
        bpk[(size_t)t * 131072 + dbase] = h;            // comp 0 (hi)
        bpk[(size_t)t * 131072 + dbase + 8192] = lo;    // comp 1 (lo)
    }
}

// ---- conv2: A slab + 6-deep async B ring + cross-phase REGISTER pipeline ----
// R11 verdict: 533us, MfmaUtil 49%. Three scheduling attacks all land
// 533-564 -> HIP-source ceiling for this barrier structure. FROZEN.
static __device__ __forceinline__ f32x4 mfma16(short8 a, short8 b, f32x4 c) {
    return __builtin_amdgcn_mfma_f32_16x16x32_bf16(a, b, c, 0, 0, 0);
}

struct FragR { short8 ah[5], al[5], bh0, bh1, bl0, bl1; };

template<int NMF>
static __device__ __forceinline__ void pre_fragR(
    FragR& f, const ushort* A_lds, const ushort* Bb, int tn,
    const int* celloff, int bro0, int bro1) {
    int kh = tn / 9, kw = tn - kh * 9;
    int tapoff = (kh * 20 + kw) * 40;
    const ushort* Bc = Bb + (tn % 6) * 8192;
#pragma unroll
    for (int i = 0; i < NMF; ++i) {
        f.ah[i] = *(const short8*)(A_lds + tapoff + celloff[i]);
        f.al[i] = *(const short8*)(A_lds + 16000 + tapoff + celloff[i]);
    }
    f.bh0 = *(const short8*)(Bc + bro0);
    f.bh1 = *(const short8*)(Bc + bro1);
    f.bl0 = *(const short8*)(Bc + 4096 + bro0);
    f.bl1 = *(const short8*)(Bc + 4096 + bro1);
}

template<int NMF>
static __device__ __forceinline__ void mfma_fragR(f32x4 (&acc)[5][2], const FragR& f) {
#pragma unroll
    for (int i = 0; i < NMF; ++i) {
        acc[i][0] = mfma16(f.ah[i], f.bh0, acc[i][0]);
        acc[i][1] = mfma16(f.ah[i], f.bh1, acc[i][1]);
    }
#pragma unroll
    for (int i = 0; i < NMF; ++i) {
        acc[i][0] = mfma16(f.ah[i], f.bl0, acc[i][0]);
        acc[i][1] = mfma16(f.ah[i], f.bl1, acc[i][1]);
    }
#pragma unroll
    for (int i = 0; i < NMF; ++i) {
        acc[i][0] = mfma16(f.al[i], f.bh0, acc[i][0]);
        acc[i][1] = mfma16(f.al[i], f.bh1, acc[i][1]);
    }
}

static __device__ __forceinline__ void stage_tap(
    const ushort* gB0, ushort* lB0, int tn, size_t gicc) {
    if (tn <= 80) {
        size_t g = (size_t)tn * 131072 + gicc;
        ushort* d = lB0 + (tn % 6) * 8192;
        gload16(gB0 + g, d);
        gload16(gB0 + g + 512, d + 512);
    }
}

template<int MF0, int NMF>
static __device__ __forceinline__ void conv2s_epi(
    const f32x4 (&acc)[5][2], const float* __restrict__ bias,
    float* __restrict__ p, int b, int oc0, int nq, int r, int kq) {
#pragma unroll
    for (int j = 0; j < 2; ++j) {
        int oc = oc0 + (nq * 2 + j) * 16 + r;
        float bv = bias[oc];
#pragma unroll
        for (int i = 0; i < NMF; ++i) {
            int row = b * 144 + (MF0 + i) * 16 + kq * 4;
#pragma unroll
            for (int reg = 0; reg < 4; ++reg)
                p[(size_t)(row + reg) * 256 + oc] = acc[i][j][reg] + bv;
        }
    }
}

__global__ __launch_bounds__(512)
__attribute__((amdgpu_waves_per_eu(2, 2)))
void k_conv2s(
    const ushort* __restrict__ x1h, const ushort* __restrict__ x1l,
    const ushort* __restrict__ bpk,
    const float* __restrict__ bias, float* __restrict__ p) {
    __shared__ __align__(16) ushort A_lds[32000];  // [comp 2][cell 400][pitch 40]
    __shared__ __align__(16) ushort Bb[49152];     // [buf 6][comp 2][kq 4][ocl 128][8]

    const int tid = threadIdx.x;
    const int lane = tid & 63;
    const int wv = tid >> 6;          // 0..7
    const int mh = wv >> 2;           // 0..1 (M split: frag tiles 0-4 / 5-8)
    const int nq = wv & 3;            // 0..3 (N split: 2 oc-tiles of 16 each)
    const int b  = blockIdx.x >> 1;
    const int nt = blockIdx.x & 1;
    const int oc0 = nt * 128;
    const int r = lane & 15, kq = lane >> 4;
    const int MF0r = mh ? 5 : 0;

    int celloff[5];
#pragma unroll
    for (int i = 0; i < 5; ++i) {
        int lm = (MF0r + i) * 16 + r;
        celloff[i] = ((lm / 12) * 20 + (lm % 12)) * 40 + kq * 8;
    }
    // B frag LDS offsets (ushorts, within comp plane)
    const int bro0 = kq * 1024 + ((nq * 2 + 0) * 16 + r) * 8;
    const int bro1 = kq * 1024 + ((nq * 2 + 1) * 16 + r) * 8;

    // staging assignment: wave -> (comp_w, kq_w) slice of each tap's 16KB tile
    const int comp_w = wv >> 2, kq_w = wv & 3;
    const ushort* gB0 = bpk + comp_w * 8192 + kq_w * 2048 + oc0 * 8 + lane * 8;
    ushort* lB0 = Bb + comp_w * 4096 + kq_w * 1024;

    f32x4 acc[5][2];
#pragma unroll
    for (int i = 0; i < 5; ++i)
#pragma unroll
        for (int j = 0; j < 2; ++j)
            acc[i][j] = (f32x4){0.f, 0.f, 0.f, 0.f};

    FragR fX, fY;

    for (int icc = 0; icc < 8; ++icc) {
        const size_t gicc = (size_t)icc * 16384;
        // ---- stage A slab (previous icc's final barrier protects slab) ----
#pragma unroll
        for (int rd = 0; rd < 7; ++rd) {
            int idx = rd * 512 + tid;
            if (idx < 3200) {
                int comp = (idx >= 1600) ? 1 : 0;
                int ci = idx - comp * 1600;
                int cell = ci >> 2, cc = ci & 3;
                const ushort* src = (comp ? x1l : x1h) +
                    ((size_t)b * 400 + cell) * 256 + icc * 32 + cc * 8;
                short8 val = *(const short8*)src;
                *(short8*)(A_lds + comp * 16000 + cell * 40 + cc * 8) = val;
            }
        }
        // ---- B prologue: stage taps 0..3 into ring slots 0..3 ----
        stage_tap(gB0, lB0, 0, gicc);
        stage_tap(gB0, lB0, 1, gicc);
        stage_tap(gB0, lB0, 2, gicc);
        stage_tap(gB0, lB0, 3, gicc);
        __syncthreads();   // A + B(t0..t3) ready
        // preload first two taps into registers (exposed once per icc)
        if (mh == 0) {
            pre_fragR<5>(fX, A_lds, Bb, 0, celloff, bro0, bro1);
            pre_fragR<5>(fY, A_lds, Bb, 1, celloff, bro0, bro1);
        } else {
            pre_fragR<4>(fX, A_lds, Bb, 0, celloff, bro0, bro1);
            pre_fragR<4>(fY, A_lds, Bb, 1, celloff, bro0, bro1);
        }

        // ---- 39 phases: mfma taps T,T+1 from regs; preread T+2,T+3 ----
#pragma unroll 1
        for (int ph = 0; ph < 39; ++ph) {
            const int T = ph * 2;
            stage_tap(gB0, lB0, T + 4, gicc);
            stage_tap(gB0, lB0, T + 5, gicc);
            if (mh == 0) {
                mfma_fragR<5>(acc, fX);
                mfma_fragR<5>(acc, fY);
                pre_fragR<5>(fX, A_lds, Bb, T + 2, celloff, bro0, bro1);
                pre_fragR<5>(fY, A_lds, Bb, T + 3, celloff, bro0, bro1);
            } else {
                mfma_fragR<4>(acc, fX);
                mfma_fragR<4>(acc, fY);
                pre_fragR<4>(fX, A_lds, Bb, T + 2, celloff, bro0, bro1);
                pre_fragR<4>(fY, A_lds, Bb, T + 3, celloff, bro0, bro1);
            }
            __syncthreads();
        }
        // ---- tail: taps 78,79 from regs; preread + compute tap 80 ----
        if (mh == 0) {
            mfma_fragR<5>(acc, fX);
            mfma_fragR<5>(acc, fY);
            pre_fragR<5>(fX, A_lds, Bb, 80, celloff, bro0, bro1);
            mfma_fragR<5>(acc, fX);
        } else {
            mfma_fragR<4>(acc, fX);
            mfma_fragR<4>(acc, fY);
            pre_fragR<4>(fX, A_lds, Bb, 80, celloff, bro0, bro1);
            mfma_fragR<4>(acc, fX);
        }
        __syncthreads();   // all reads of A slab + ring done before restage
    }

    if (mh == 0) conv2s_epi<0, 5>(acc, bias, p, b, oc0, nq, r, kq);
    else         conv2s_epi<5, 4>(acc, bias, p, b, oc0, nq, r, kq);
}

// squash v2: coalesced p reads via LDS tile (R15: +20us). FROZEN.
__global__ __launch_bounds__(256) void k_squash(const float* __restrict__ p,
                                                float* __restrict__ u) {
    __shared__ float S[2048];          // [8 rows][256 oc]
    const int tid = threadIdx.x;
    const int r0 = blockIdx.x * 8;     // global row = b*144 + pos; 144%8==0
    const int b = blockIdx.x / 18;     // 18 blocks per batch image
    const int pos0 = (blockIdx.x % 18) * 8;
#pragma unroll
    for (int k = 0; k < 8; ++k)
        S[k * 256 + tid] = p[(size_t)(r0 + k) * 256 + tid];
    __syncthreads();
    const int r = tid >> 5, m = tid & 31;
    float pv[8];
    float s2 = 0.f;
#pragma unroll
    for (int i = 0; i < 8; ++i) {
        pv[i] = S[r * 256 + i * 32 + m];
        s2 = fmaf(pv[i], pv[i], s2);
    }
    float f = (s2 / (1.f + s2)) / sqrtf(s2 + 1e-8f);
    size_t n = (size_t)b * NCAP + m * NPRIM + (pos0 + r);
    float4* up = (float4*)(u + n * 8);
    up[0] = make_float4(f * pv[0], f * pv[1], f * pv[2], f * pv[3]);
    up[1] = make_float4(f * pv[4], f * pv[5], f * pv[6], f * pv[7]);
}

// transpose routing weights: Wd[n][c][o][i] -> Wtv[c][o][n][i]  (i contiguous)
__global__ __launch_bounds__(256) void k_prep_wt(const float* __restrict__ Wd,
                                                 float* __restrict__ Wtv) {
    __shared__ float S[64][129];
    int c = blockIdx.x % NCLS;
    int nt = blockIdx.x / NCLS;    // 0..71
    int n0 = nt * 64;
    int tid = threadIdx.x;
#pragma unroll
    for (int rep = 0; rep < 32; ++rep) {
        int idx = rep * 256 + tid;
        int nl = idx >> 7, oi = idx & 127;
        S[nl][oi] = Wd[(size_t)(n0 + nl) * 1280 + c * 128 + oi];
    }
    __syncthreads();
    // write Wtv[c][o][n][i]: 16 o x 64 nl items, 32B each (coalesced 2KB/wave)
#pragma unroll
    for (int rep = 0; rep < 4; ++rep) {
        int idx = rep * 256 + tid;
        int o = idx >> 6, nl = idx & 63;
        float4* d4 = (float4*)(Wtv + (((size_t)c * 16 + o) * NCAP + n0 + nl) * 8);
        d4[0] = make_float4(S[nl][o * 8 + 0], S[nl][o * 8 + 1],
                            S[nl][o * 8 + 2], S[nl][o * 8 + 3]);
        d4[1] = make_float4(S[nl][o * 8 + 4], S[nl][o * 8 + 5],
                            S[nl][o * 8 + 6], S[nl][o * 8 + 7]);
    }
}

// routing v3 (nb=4, o-SPLIT): R13 (fill cut) and R14 (issue cut) both null ->
// surviving theory: L2-READ-BW bound (5.1GB reads / 400us = 12.8 TB/s).
// nb=4 halves Wt reads (4.5->2.25GB). Register wall (128, R9/R12 lesson)
// respected by splitting the 16 o across wave-pairs (oh = tid>>7, 8 o each):
// per-thread uv[4][8]+uh[4][8]+sS[4][8] ~ 120 live. bij in LDS; per-j
// cross-half agreement via parity-double-buffered agrL (1 barrier/j, iters
// 1-2 only; oh is wave-uniform -> no divergence). Reassociated sums only.
__global__ __launch_bounds__(256) void k_route7(const float* __restrict__ u,
                                                const float* __restrict__ Wtv,
                                                float* __restrict__ v_out) {
    __shared__ float bijL[4][36][128];     // 73.7 KB  [bb][j][nl]
    __shared__ float agrL[2][2][4][128];   // 8 KB     [j&1][oh][bb][nl]
    __shared__ float part[4][4][9];        // [wave][bb][sZ + 8 sS]
    __shared__ float sums[4][17];
    __shared__ float vsh[4][16];
    int id = blockIdx.x;
    int c, bg;
    if (id < 256) { c = id & 7; bg = id >> 3; }           // classes 0..7: one XCD each
    else { int rr = id - 256; c = 8 + (rr >> 5); bg = rr & 31; }  // classes 8,9
    int b0 = bg * 4;
    int tid = threadIdx.x;
    int oh = tid >> 7;          // o-half (wave-uniform)
    int nl = tid & 127;
    int lane = tid & 63, wvi = tid >> 6;
    const float* WtC = Wtv + ((size_t)c * 16 + oh * 8) * NCAP * 8;

    for (int iter = 0; iter < 3; ++iter) {
        float sZ[4] = {0.f, 0.f, 0.f, 0.f};
        float sS[4][8];
#pragma unroll
        for (int bb = 0; bb < 4; ++bb)
#pragma unroll
            for (int oo = 0; oo < 8; ++oo) sS[bb][oo] = 0.f;

        for (int j = 0; j < 36; ++j) {
            int n = j * 128 + nl;
            float uv[4][8];
#pragma unroll
            for (int bb = 0; bb < 4; ++bb) {
                const float4* up = (const float4*)(u + ((size_t)(b0 + bb) * NCAP + n) * 8);
                float4 a = up[0], d = up[1];
                uv[bb][0] = a.x; uv[bb][1] = a.y; uv[bb][2] = a.z; uv[bb][3] = a.w;
                uv[bb][4] = d.x; uv[bb][5] = d.y; uv[bb][6] = d.z; uv[bb][7] = d.w;
            }
            float uh[4][8];
#pragma unroll
            for (int oo = 0; oo < 8; ++oo) {
                const float4* wp = (const float4*)(WtC + ((size_t)oo * NCAP + n) * 8);
                float4 w0 = wp[0], w1 = wp[1];
                float w[8] = {w0.x, w0.y, w0.z, w0.w, w1.x, w1.y, w1.z, w1.w};
#pragma unroll
                for (int bb = 0; bb < 4; ++bb) {
                    float s = 0.f;
#pragma unroll
                    for (int i = 0; i < 8; ++i) s = fmaf(w[i], uv[bb][i], s);
                    uh[bb][oo] = s;
                }
            }
            float e[4];
            if (iter == 0) {
                e[0] = e[1] = e[2] = e[3] = 1.f;
            } else {
                float* agW = &agrL[j & 1][oh][0][0];
#pragma unroll
                for (int bb = 0; bb < 4; ++bb) {
                    float ag = 0.f;
#pragma unroll
                    for (int oo = 0; oo < 8; ++oo)
                        ag = fmaf(uh[bb][oo], vsh[bb][oh * 8 + oo], ag);
                    agW[bb * 128 + nl] = ag;
                }
                __syncthreads();
                const float* ag0 = &agrL[j & 1][0][0][0];
                const float* ag1 = &agrL[j & 1][1][0][0];
#pragma unroll
                for (int bb = 0; bb < 4; ++bb) {
                    float bold = (iter == 1) ? 0.f : bijL[bb][j][nl];
                    float bnew = bold + ag0[bb * 128 + nl] + ag1[bb * 128 + nl];
                    if (oh == 0) bijL[bb][j][nl] = bnew;
                    e[bb] = __expf(bnew);
                }
                // parity double-buffer: next j writes the other agrL plane,
                // so no second barrier needed before overwrite.
            }
#pragma unroll
            for (int bb = 0; bb < 4; ++bb) {
                if (oh == 0) sZ[bb] += e[bb];      // wave-uniform branch
#pragma unroll
                for (int oo = 0; oo < 8; ++oo)
                    sS[bb][oo] = fmaf(e[bb], uh[bb][oo], sS[bb][oo]);
            }
        }

        // ---- block reduction ----
#pragma unroll
        for (int bb = 0; bb < 4; ++bb) {
            float z = sZ[bb];
#pragma unroll
            for (int d = 32; d >= 1; d >>= 1) z += __shfl_xor(z, d, 64);
            if (lane == 0) part[wvi][bb][0] = z;
#pragma unroll
            for (int oo = 0; oo < 8; ++oo) {
                float s = sS[bb][oo];
#pragma unroll
                for (int d = 32; d >= 1; d >>= 1) s += __shfl_xor(s, d, 64);
                if (lane == 0) part[wvi][bb][1 + oo] = s;
            }
        }
        __syncthreads();
        if (tid < 68) {
            int bb = tid / 17, k = tid % 17;
            float s;
            if (k == 0) s = part[0][bb][0] + part[1][bb][0];            // sZ: oh==0 waves
            else {
                int o = k - 1;
                if (o < 8) s = part[0][bb][1 + o] + part[1][bb][1 + o]; // half 0
                else       s = part[2][bb][o - 7] + part[3][bb][o - 7]; // half 1 ([1+(o-8)])
            }
            sums[bb][k] = s;
        }
        __syncthreads();
        if (tid < 4) {
            float Z = sums[tid][0];
            float s[16];
            float s2 = 0.f;
#pragma unroll
            for (int o = 0; o < 16; ++o) {
                s[o] = sums[tid][1 + o] / Z;
                s2 = fmaf(s[o], s[o], s2);
            }
            float f = (s2 / (1.f + s2)) / sqrtf(s2 + 1e-8f);
#pragma unroll
            for (int o = 0; o < 16; ++o) vsh[tid][o] = f * s[o];
        }
        __syncthreads();
    }
    if (tid < 64) {
        int bb = tid >> 4, o = tid & 15;
        v_out[((size_t)(b0 + bb) * NCLS + c) * 16 + o] = vsh[bb][o];
    }
}

// head: v_length, argmax, one-hot
__global__ __launch_bounds__(64) void k_head(const float* __restrict__ v,
                                             float* __restrict__ out,
                                             int* __restrict__ cls_ws) {
    __shared__ float len2[NCLS];
    __shared__ int cls_sh;
    int b = blockIdx.x, tid = threadIdx.x;
    if (tid < NCLS) {
        float s2 = 0.f;
#pragma unroll
        for (int o = 0; o < 16; ++o) {
            float t = v[((size_t)b * NCLS + tid) * 16 + o];
            s2 = fmaf(t, t, s2);
        }
        len2[tid] = s2;
        out[OUT_LEN + b * NCLS + tid] = sqrtf(s2);
    }
    __syncthreads();
    if (tid == 0) {
        int best = 0;
        float bv = len2[0];
        for (int c2 = 1; c2 < NCLS; ++c2)
            if (len2[c2] > bv) { bv = len2[c2]; best = c2; }
        cls_sh = best;
        cls_ws[b] = best;
    }
    __syncthreads();
    if (tid < NCLS) out[b * NCLS + tid] = (tid == cls_sh) ? 1.0f : 0.0f;
}

// decoder layer 1
__global__ __launch_bounds__(256) void k_dec1(const float* __restrict__ v,
                                              const int* __restrict__ cls_ws,
                                              const float* __restrict__ w1,
                                              const float* __restrict__ b1,
                                              float* __restrict__ h1) {
    int id = blockIdx.x * 256 + threadIdx.x;  // B*512
    int j = id % 512, b = id / 512;
    int cls = cls_ws[b];
    const float* vp = v + ((size_t)b * NCLS + cls) * 16;
    float acc = b1[j];
#pragma unroll
    for (int o = 0; o < 16; ++o)
        acc = fmaf(vp[o], w1[(size_t)(cls * 16 + o) * 512 + j], acc);
    h1[id] = fmaxf(acc, 0.f);
}

// decoder layer 2
__global__ __launch_bounds__(256) void k_dec2(const float* __restrict__ h1,
                                              const float* __restrict__ w2,
                                              const float* __restrict__ b2,
                                              float* __restrict__ h2) {
    __shared__ float hs[512];
    int bi = blockIdx.x;
    int jc = bi % 4;
    int b = bi / 4;
    int tid = threadIdx.x;
    hs[tid] = h1[b * 512 + tid];
    hs[tid + 256] = h1[b * 512 + tid + 256];
    __syncthreads();
    int j = jc * 256 + tid;
    float acc = b2[j];
#pragma unroll 8
    for (int k = 0; k < 512; ++k)
        acc = fmaf(hs[k], w2[(size_t)k * 1024 + j], acc);
    h2[b * 1024 + j] = fmaxf(acc, 0.f);
}

// decoder layer 3 + sigmoid
__global__ __launch_bounds__(256) void k_dec3(const float* __restrict__ h2,
                                              const float* __restrict__ w3,
                                              const float* __restrict__ b3,
                                              float* __restrict__ out) {
    __shared__ float hs[1024];
    int bi = blockIdx.x;
    int jc = bi % 4;
    int b = bi / 4;
    int tid = threadIdx.x;
#pragma unroll
    for (int t = 0; t < 4; ++t) hs[tid + t * 256] = h2[b * 1024 + tid + t * 256];
    __syncthreads();
    int j = jc * 256 + tid;
    if (j < 784) {
        float acc = b3[j];
#pragma unroll 8
        for (int k = 0; k < 1024; ++k)
            acc = fmaf(hs[k], w3[(size_t)k * 784 + j], acc);
        out[OUT_REC + b * 784 + j] = 1.f / (1.f + __expf(-acc));
    }
}

// ---------------- launcher ----------------
extern "C" void kernel_launch(void* const* d_in, const int* in_sizes, int n_in,
                              void* d_out, int out_size, void* d_ws, size_t ws_size,
                              hipStream_t stream) {
    const float* imgs = (const float*)d_in[0];
    const float* c1w  = (const float*)d_in[1];
    const float* c1b  = (const float*)d_in[2];
    const float* c2w  = (const float*)d_in[3];
    const float* c2b  = (const float*)d_in[4];
    const float* Wd   = (const float*)d_in[5];
    const float* dw1  = (const float*)d_in[6];
    const float* db1  = (const float*)d_in[7];
    const float* dw2  = (const float*)d_in[8];
    const float* db2  = (const float*)d_in[9];
    const float* dw3  = (const float*)d_in[10];
    const float* db3  = (const float*)d_in[11];

    float* out = (float*)d_out;
    float* ws  = (float*)d_ws;
    ushort* x1h = (ushort*)(ws + WS_X1H);
    ushort* x1l = (ushort*)(ws + WS_X1L);
    ushort* bpk = (ushort*)(ws + WS_BH);   // 81*131072 ushorts = 21.23 MB
    float* p    = ws + WS_P;
    float* u    = ws + WS_U;
    float* v    = ws + WS_V;
    float* h1   = ws + WS_H1;
    float* h2   = ws + WS_H2;
    int*   cls  = (int*)(ws + WS_CLS);
    float* wtv  = ws + WS_X1H;   // reuses x1h region (dead after k_conv2s)

    k_conv1<<<BB * 20, 256, 0, stream>>>(imgs, c1w, c1b, x1h, x1l);
    k_prep_w2<<<256, 256, 0, stream>>>(c2w, bpk);
    k_conv2s<<<BB * 2, 512, 0, stream>>>(x1h, x1l, bpk, c2b, p);
    k_squash<<<BB * NCAP / 256, 256, 0, stream>>>(p, u);
    k_prep_wt<<<720, 256, 0, stream>>>(Wd, wtv);   // after conv2s: x1h region now free
    k_route7<<<(BB / 4) * NCLS, 256, 0, stream>>>(u, wtv, v);
    k_head<<<BB, 64, 0, stream>>>(v, out, cls);
    k_dec1<<<BB * 512 / 256, 256, 0, stream>>>(v, cls, dw1, db1, h1);
    k_dec2<<<BB * 4, 256, 0, stream>>>(h1, dw2, db2, h2);
    k_dec3<<<BB * 4, 256, 0, stream>>>(h2, dw3, db3, out);
}

// Round 18
// 1067.533 us; speedup vs baseline: 1.0710x; 1.0407x over previous
//
#include <hip/hip_runtime.h>
#include <cstdint>
#include <cstddef>

// ---------------- problem constants ----------------
#define BB 128
#define NMAP 32
#define NPRIM 144
#define NCAP 4608      // 32*144
#define NCLS 10
#define ODIM 16
#define IDIM 8

// ws layout (float offsets)
#define WS_X1H  0                       // x1 hi bf16 NHWC ushort; later reused for Wtv fp32 (5.9M fl)
#define WS_X1L  6553600                 // x1 lo bf16
#define WS_BH   13107200                // packed conv2 weights Bpk: [81 t][8 icc][2 comp][4 kq][256 oc][8] ushort
#define WS_P    18415616                // conv2 out NHWC: [128*144][256]
#define WS_U    23134208                // squash:   [128][4608][8]
#define WS_V    27852800                // routing v: [128][10][16]
#define WS_H1   27873280                // dec h1: [128][512]
#define WS_H2   27938816                // dec h2: [128][1024]
#define WS_CLS  28069888                // argmax class per b (int), 128

// out layout (floats): [128*10 onehot][128*784 reconst][128*10 v_length]
#define OUT_REC  1280
#define OUT_LEN  101632

typedef __attribute__((ext_vector_type(8))) short short8;
typedef __attribute__((ext_vector_type(4))) float f32x4;

// round-to-nearest-even fp32 -> bf16 bits
static __device__ __forceinline__ ushort f2bf(float f) {
    uint u = __float_as_uint(f);
    u = (u + 0x7FFFu + ((u >> 16) & 1u)) >> 16;
    return (ushort)u;
}
static __device__ __forceinline__ float bf2f(ushort h) {
    return __uint_as_float(((uint)h) << 16);
}

// async global->LDS, 16B per lane. Global addr is PER-LANE; LDS dest is
// wave-uniform base + lane*16 (HW-added).
static __device__ __forceinline__ void gload16(const ushort* g, ushort* l) {
    __builtin_amdgcn_global_load_lds(
        (const __attribute__((address_space(1))) void*)g,
        (__attribute__((address_space(3))) void*)l, 16, 0, 0);
}

// ---------------- kernels ----------------

// conv1 + bias + relu, emitting NHWC bf16 hi/lo directly.
__global__ __launch_bounds__(256) void k_conv1(const float* __restrict__ img,
                                               const float* __restrict__ w,
                                               const float* __restrict__ bias,
                                               ushort* __restrict__ x1h,
                                               ushort* __restrict__ x1l) {
    __shared__ float simg[252];   // 9 rows x 28 cols
    int bi = blockIdx.x;
    int y = bi % 20;
    int b = bi / 20;
    int oc = threadIdx.x;
    if (threadIdx.x < 252)
        simg[threadIdx.x] = img[(size_t)b * 784 + y * 28 + threadIdx.x];
    __syncthreads();

    float acc[20];
    float bv = bias[oc];
#pragma unroll
    for (int x = 0; x < 20; ++x) acc[x] = bv;
    const float* wp = w + oc * 81;
#pragma unroll
    for (int kh = 0; kh < 9; ++kh) {
        float r[28];
#pragma unroll
        for (int j = 0; j < 28; ++j) r[j] = simg[kh * 28 + j];
#pragma unroll
        for (int kw = 0; kw < 9; ++kw) {
            float wv = wp[kh * 9 + kw];
#pragma unroll
            for (int x = 0; x < 20; ++x)
                acc[x] = fmaf(wv, r[x + kw], acc[x]);
        }
    }
    size_t base = ((size_t)b * 400 + y * 20) * 256 + oc;
#pragma unroll
    for (int x = 0; x < 20; ++x) {
        float v = fmaxf(acc[x], 0.f);
        ushort h = f2bf(v);
        ushort lo = f2bf(v - bf2f(h));
        x1h[base + (size_t)x * 256] = h;
        x1l[base + (size_t)x * 256] = lo;
    }
}

// conv2 weights repack for LDS staging:
// w2[oc][ic][81] fp32 -> Bpk[t][icc][comp][kq][oc 256][ic8 8] bf16 hi/lo.
__global__ __launch_bounds__(256) void k_prep_w2(const float* __restrict__ w2,
                                                 ushort* __restrict__ bpk) {
    int blk = blockIdx.x;            // 256 = icc*32 + kq*8 + ocg
    int icc = blk >> 5, kq = (blk >> 3) & 3, ocg = blk & 7;
    int tid = threadIdx.x;
    int ocl = tid >> 3, ic8 = tid & 7;
    int oc = ocg * 32 + ocl;
    int ic = icc * 32 + kq * 8 + ic8;
    const float* src = w2 + ((size_t)oc * 256 + ic) * 81;
    size_t dbase = (size_t)icc * 16384 + (size_t)kq * 2048 + (size_t)oc * 8 + ic8;
#pragma unroll 9
    for (int t = 0; t < 81; ++t) {
        float v = src[t];
        ushort h = f2bf(v);
        ushort lo = f2bf(v - bf2f(h));
        bpk[(size_t)t * 131072 + dbase] = h;            // comp 0 (hi)
        bpk[(size_t)t * 131072 + dbase + 8192] = lo;    // comp 1 (lo)
    }
}

// ---- conv2: A slab + 6-deep async B ring + cross-phase REGISTER pipeline ----
// R11 verdict: 533us, MfmaUtil 49%. Three scheduling attacks all land
// 533-564 -> HIP-source ceiling for this barrier structure. FROZEN.
static __device__ __forceinline__ f32x4 mfma16(short8 a, short8 b, f32x4 c) {
    return __builtin_amdgcn_mfma_f32_16x16x32_bf16(a, b, c, 0, 0, 0);
}

struct FragR { short8 ah[5], al[5], bh0, bh1, bl0, bl1; };

template<int NMF>
static __device__ __forceinline__ void pre_fragR(
    FragR& f, const ushort* A_lds, const ushort* Bb, int tn,
    const int* celloff, int bro0, int bro1) {
    int kh = tn / 9, kw = tn - kh * 9;
    int tapoff = (kh * 20 + kw) * 40;
    const ushort* Bc = Bb + (tn % 6) * 8192;
#pragma unroll
    for (int i = 0; i < NMF; ++i) {
        f.ah[i] = *(const short8*)(A_lds + tapoff + celloff[i]);
        f.al[i] = *(const short8*)(A_lds + 16000 + tapoff + celloff[i]);
    }
    f.bh0 = *(const short8*)(Bc + bro0);
    f.bh1 = *(const short8*)(Bc + bro1);
    f.bl0 = *(const short8*)(Bc + 4096 + bro0);
    f.bl1 = *(const short8*)(Bc + 4096 + bro1);
}

template<int NMF>
static __device__ __forceinline__ void mfma_fragR(f32x4 (&acc)[5][2], const FragR& f) {
#pragma unroll
    for (int i = 0; i < NMF; ++i) {
        acc[i][0] = mfma16(f.ah[i], f.bh0, acc[i][0]);
        acc[i][1] = mfma16(f.ah[i], f.bh1, acc[i][1]);
    }
#pragma unroll
    for (int i = 0; i < NMF; ++i) {
        acc[i][0] = mfma16(f.ah[i], f.bl0, acc[i][0]);
        acc[i][1] = mfma16(f.ah[i], f.bl1, acc[i][1]);
    }
#pragma unroll
    for (int i = 0; i < NMF; ++i) {
        acc[i][0] = mfma16(f.al[i], f.bh0, acc[i][0]);
        acc[i][1] = mfma16(f.al[i], f.bh1, acc[i][1]);
    }
}

static __device__ __forceinline__ void stage_tap(
    const ushort* gB0, ushort* lB0, int tn, size_t gicc) {
    if (tn <= 80) {
        size_t g = (size_t)tn * 131072 + gicc;
        ushort* d = lB0 + (tn % 6) * 8192;
        gload16(gB0 + g, d);
        gload16(gB0 + g + 512, d + 512);
    }
}

template<int MF0, int NMF>
static __device__ __forceinline__ void conv2s_epi(
    const f32x4 (&acc)[5][2], const float* __restrict__ bias,
    float* __restrict__ p, int b, int oc0, int nq, int r, int kq) {
#pragma unroll
    for (int j = 0; j < 2; ++j) {
        int oc = oc0 + (nq * 2 + j) * 16 + r;
        float bv = bias[oc];
#pragma unroll
        for (int i = 0; i < NMF; ++i) {
            int row = b * 144 + (MF0 + i) * 16 + kq * 4;
#pragma unroll
            for (int reg = 0; reg < 4; ++reg)
                p[(size_t)(row + reg) * 256 + oc] = acc[i][j][reg] + bv;
        }
    }
}

__global__ __launch_bounds__(512)
__attribute__((amdgpu_waves_per_eu(2, 2)))
void k_conv2s(
    const ushort* __restrict__ x1h, const ushort* __restrict__ x1l,
    const ushort* __restrict__ bpk,
    const float* __restrict__ bias, float* __restrict__ p) {
    __shared__ __align__(16) ushort A_lds[32000];  // [comp 2][cell 400][pitch 40]
    __shared__ __align__(16) ushort Bb[49152];     // [buf 6][comp 2][kq 4][ocl 128][8]

    const int tid = threadIdx.x;
    const int lane = tid & 63;
    const int wv = tid >> 6;          // 0..7
    const int mh = wv >> 2;           // 0..1 (M split: frag tiles 0-4 / 5-8)
    const int nq = wv & 3;            // 0..3 (N split: 2 oc-tiles of 16 each)
    const int b  = blockIdx.x >> 1;
    const int nt = blockIdx.x & 1;
    const int oc0 = nt * 128;
    const int r = lane & 15, kq = lane >> 4;
    const int MF0r = mh ? 5 : 0;

    int celloff[5];
#pragma unroll
    for (int i = 0; i < 5; ++i) {
        int lm = (MF0r + i) * 16 + r;
        celloff[i] = ((lm / 12) * 20 + (lm % 12)) * 40 + kq * 8;
    }
    // B frag LDS offsets (ushorts, within comp plane)
    const int bro0 = kq * 1024 + ((nq * 2 + 0) * 16 + r) * 8;
    const int bro1 = kq * 1024 + ((nq * 2 + 1) * 16 + r) * 8;

    // staging assignment: wave -> (comp_w, kq_w) slice of each tap's 16KB tile
    const int comp_w = wv >> 2, kq_w = wv & 3;
    const ushort* gB0 = bpk + comp_w * 8192 + kq_w * 2048 + oc0 * 8 + lane * 8;
    ushort* lB0 = Bb + comp_w * 4096 + kq_w * 1024;

    f32x4 acc[5][2];
#pragma unroll
    for (int i = 0; i < 5; ++i)
#pragma unroll
        for (int j = 0; j < 2; ++j)
            acc[i][j] = (f32x4){0.f, 0.f, 0.f, 0.f};

    FragR fX, fY;

    for (int icc = 0; icc < 8; ++icc) {
        const size_t gicc = (size_t)icc * 16384;
        // ---- stage A slab (previous icc's final barrier protects slab) ----
#pragma unroll
        for (int rd = 0; rd < 7; ++rd) {
            int idx = rd * 512 + tid;
            if (idx < 3200) {
                int comp = (idx >= 1600) ? 1 : 0;
                int ci = idx - comp * 1600;
                int cell = ci >> 2, cc = ci & 3;
                const ushort* src = (comp ? x1l : x1h) +
                    ((size_t)b * 400 + cell) * 256 + icc * 32 + cc * 8;
                short8 val = *(const short8*)src;
                *(short8*)(A_lds + comp * 16000 + cell * 40 + cc * 8) = val;
            }
        }
        // ---- B prologue: stage taps 0..3 into ring slots 0..3 ----
        stage_tap(gB0, lB0, 0, gicc);
        stage_tap(gB0, lB0, 1, gicc);
        stage_tap(gB0, lB0, 2, gicc);
        stage_tap(gB0, lB0, 3, gicc);
        __syncthreads();   // A + B(t0..t3) ready
        // preload first two taps into registers (exposed once per icc)
        if (mh == 0) {
            pre_fragR<5>(fX, A_lds, Bb, 0, celloff, bro0, bro1);
            pre_fragR<5>(fY, A_lds, Bb, 1, celloff, bro0, bro1);
        } else {
            pre_fragR<4>(fX, A_lds, Bb, 0, celloff, bro0, bro1);
            pre_fragR<4>(fY, A_lds, Bb, 1, celloff, bro0, bro1);
        }

        // ---- 39 phases: mfma taps T,T+1 from regs; preread T+2,T+3 ----
#pragma unroll 1
        for (int ph = 0; ph < 39; ++ph) {
            const int T = ph * 2;
            stage_tap(gB0, lB0, T + 4, gicc);
            stage_tap(gB0, lB0, T + 5, gicc);
            if (mh == 0) {
                mfma_fragR<5>(acc, fX);
                mfma_fragR<5>(acc, fY);
                pre_fragR<5>(fX, A_lds, Bb, T + 2, celloff, bro0, bro1);
                pre_fragR<5>(fY, A_lds, Bb, T + 3, celloff, bro0, bro1);
            } else {
                mfma_fragR<4>(acc, fX);
                mfma_fragR<4>(acc, fY);
                pre_fragR<4>(fX, A_lds, Bb, T + 2, celloff, bro0, bro1);
                pre_fragR<4>(fY, A_lds, Bb, T + 3, celloff, bro0, bro1);
            }
            __syncthreads();
        }
        // ---- tail: taps 78,79 from regs; preread + compute tap 80 ----
        if (mh == 0) {
            mfma_fragR<5>(acc, fX);
            mfma_fragR<5>(acc, fY);
            pre_fragR<5>(fX, A_lds, Bb, 80, celloff, bro0, bro1);
            mfma_fragR<5>(acc, fX);
        } else {
            mfma_fragR<4>(acc, fX);
            mfma_fragR<4>(acc, fY);
            pre_fragR<4>(fX, A_lds, Bb, 80, celloff, bro0, bro1);
            mfma_fragR<4>(acc, fX);
        }
        __syncthreads();   // all reads of A slab + ring done before restage
    }

    if (mh == 0) conv2s_epi<0, 5>(acc, bias, p, b, oc0, nq, r, kq);
    else         conv2s_epi<5, 4>(acc, bias, p, b, oc0, nq, r, kq);
}

// squash v2: coalesced p reads via LDS tile (R15: +20us). FROZEN.
__global__ __launch_bounds__(256) void k_squash(const float* __restrict__ p,
                                                float* __restrict__ u) {
    __shared__ float S[2048];          // [8 rows][256 oc]
    const int tid = threadIdx.x;
    const int r0 = blockIdx.x * 8;     // global row = b*144 + pos; 144%8==0
    const int b = blockIdx.x / 18;     // 18 blocks per batch image
    const int pos0 = (blockIdx.x % 18) * 8;
#pragma unroll
    for (int k = 0; k < 8; ++k)
        S[k * 256 + tid] = p[(size_t)(r0 + k) * 256 + tid];
    __syncthreads();
    const int r = tid >> 5, m = tid & 31;
    float pv[8];
    float s2 = 0.f;
#pragma unroll
    for (int i = 0; i < 8; ++i) {
        pv[i] = S[r * 256 + i * 32 + m];
        s2 = fmaf(pv[i], pv[i], s2);
    }
    float f = (s2 / (1.f + s2)) / sqrtf(s2 + 1e-8f);
    size_t n = (size_t)b * NCAP + m * NPRIM + (pos0 + r);
    float4* up = (float4*)(u + n * 8);
    up[0] = make_float4(f * pv[0], f * pv[1], f * pv[2], f * pv[3]);
    up[1] = make_float4(f * pv[4], f * pv[5], f * pv[6], f * pv[7]);
}

// transpose routing weights: Wd[n][c][o][i] -> Wtv[c][o][n][i]  (i contiguous)
__global__ __launch_bounds__(256) void k_prep_wt(const float* __restrict__ Wd,
                                                 float* __restrict__ Wtv) {
    __shared__ float S[64][129];
    int c = blockIdx.x % NCLS;
    int nt = blockIdx.x / NCLS;    // 0..71
    int n0 = nt * 64;
    int tid = threadIdx.x;
#pragma unroll
    for (int rep = 0; rep < 32; ++rep) {
        int idx = rep * 256 + tid;
        int nl = idx >> 7, oi = idx & 127;
        S[nl][oi] = Wd[(size_t)(n0 + nl) * 1280 + c * 128 + oi];
    }
    __syncthreads();
    // write Wtv[c][o][n][i]: 16 o x 64 nl items, 32B each (coalesced 2KB/wave)
#pragma unroll
    for (int rep = 0; rep < 4; ++rep) {
        int idx = rep * 256 + tid;
        int o = idx >> 6, nl = idx & 63;
        float4* d4 = (float4*)(Wtv + (((size_t)c * 16 + o) * NCAP + n0 + nl) * 8);
        d4[0] = make_float4(S[nl][o * 8 + 0], S[nl][o * 8 + 1],
                            S[nl][o * 8 + 2], S[nl][o * 8 + 3]);
        d4[1] = make_float4(S[nl][o * 8 + 4], S[nl][o * 8 + 5],
                            S[nl][o * 8 + 6], S[nl][o * 8 + 7]);
    }
}

// routing v4: nb=4 BYTE-SAVINGS + route5-level TLP, decoupled.
// R16 inference: nb=4 halved both Wt bytes AND TLP with net +13us -> the two
// effects nearly cancel -> restore TLP at nb=4: 512-thread blocks (8 waves),
// grid 320 -> 10 waves/CU (= route5) with half the Wt stream.
// Also fixes route7's latent race: bold is read BEFORE the agreement barrier,
// so the single barrier orders all bij reads before all bij writes.
// (R17 bench lost to GPU-broker timeout; identical kernel resubmitted.)
__global__ __launch_bounds__(512) void k_route8(const float* __restrict__ u,
                                                const float* __restrict__ Wtv,
                                                float* __restrict__ v_out) {
    __shared__ float bijL[4][18][256];     // 73.7 KB [bb][j][nl]
    __shared__ float agrL[2][2][4][256];   // 16 KB   [j&1][oh][bb][nl]
    __shared__ float part[8][4][9];        // [wave][bb][sZ + 8 sS]
    __shared__ float sums[4][17];
    __shared__ float vsh[4][16];
    int id = blockIdx.x;
    int c, bg;
    if (id < 256) { c = id & 7; bg = id >> 3; }           // classes 0..7: one XCD each
    else { int rr = id - 256; c = 8 + (rr >> 5); bg = rr & 31; }  // classes 8,9
    int b0 = bg * 4;
    int tid = threadIdx.x;
    int oh = tid >> 8;          // o-half (wave-uniform: waves 0-3 vs 4-7)
    int nl = tid & 255;
    int lane = tid & 63, wvi = tid >> 6;
    const float* WtC = Wtv + ((size_t)c * 16 + oh * 8) * (size_t)NCAP * 8;

    for (int iter = 0; iter < 3; ++iter) {
        float sZ[4] = {0.f, 0.f, 0.f, 0.f};
        float sS[4][8];
#pragma unroll
        for (int bb = 0; bb < 4; ++bb)
#pragma unroll
            for (int oo = 0; oo < 8; ++oo) sS[bb][oo] = 0.f;

        for (int j = 0; j < 18; ++j) {
            int n = j * 256 + nl;
            float uv[4][8];
#pragma unroll
            for (int bb = 0; bb < 4; ++bb) {
                const float4* up = (const float4*)(u + ((size_t)(b0 + bb) * NCAP + n) * 8);
                float4 a = up[0], d = up[1];
                uv[bb][0] = a.x; uv[bb][1] = a.y; uv[bb][2] = a.z; uv[bb][3] = a.w;
                uv[bb][4] = d.x; uv[bb][5] = d.y; uv[bb][6] = d.z; uv[bb][7] = d.w;
            }
            float uh[4][8];
#pragma unroll
            for (int oo = 0; oo < 8; ++oo) {
                const float4* wp = (const float4*)(WtC + ((size_t)oo * NCAP + n) * 8);
                float4 w0 = wp[0], w1 = wp[1];
                float w[8] = {w0.x, w0.y, w0.z, w0.w, w1.x, w1.y, w1.z, w1.w};
#pragma unroll
                for (int bb = 0; bb < 4; ++bb) {
                    float s = 0.f;
#pragma unroll
                    for (int i = 0; i < 8; ++i) s = fmaf(w[i], uv[bb][i], s);
                    uh[bb][oo] = s;
                }
            }
            float e[4];
            if (iter == 0) {
                e[0] = e[1] = e[2] = e[3] = 1.f;
            } else {
                // (1) write my half's agreement; (2) read bold BEFORE barrier
                //     (prev writes to bijL[.][j][.] were last iter, ordered by
                //      the iter-end barriers); (3) barrier orders everything.
                float* agW = &agrL[j & 1][oh][0][0];
#pragma unroll
                for (int bb = 0; bb < 4; ++bb) {
                    float ag = 0.f;
#pragma unroll
                    for (int oo = 0; oo < 8; ++oo)
                        ag = fmaf(uh[bb][oo], vsh[bb][oh * 8 + oo], ag);
                    agW[bb * 256 + nl] = ag;
                }
                float bold[4];
#pragma unroll
                for (int bb = 0; bb < 4; ++bb)
                    bold[bb] = (iter == 1) ? 0.f : bijL[bb][j][nl];
                __syncthreads();
                const float* ag0 = &agrL[j & 1][0][0][0];
                const float* ag1 = &agrL[j & 1][1][0][0];
#pragma unroll
                for (int bb = 0; bb < 4; ++bb) {
                    float bnew = bold[bb] + ag0[bb * 256 + nl] + ag1[bb * 256 + nl];
                    if (oh == 0) bijL[bb][j][nl] = bnew;   // next-iter bold
                    e[bb] = __expf(bnew);
                }
                // parity double-buffer + the j+1 barrier make agrL reuse safe.
            }
#pragma unroll
            for (int bb = 0; bb < 4; ++bb) {
                if (oh == 0) sZ[bb] += e[bb];      // wave-uniform; count once
#pragma unroll
                for (int oo = 0; oo < 8; ++oo)
                    sS[bb][oo] = fmaf(e[bb], uh[bb][oo], sS[bb][oo]);
            }
        }

        // ---- block reduction ----
#pragma unroll
        for (int bb = 0; bb < 4; ++bb) {
            float z = sZ[bb];
#pragma unroll
            for (int d = 32; d >= 1; d >>= 1) z += __shfl_xor(z, d, 64);
            if (lane == 0) part[wvi][bb][0] = z;
#pragma unroll
            for (int oo = 0; oo < 8; ++oo) {
                float s = sS[bb][oo];
#pragma unroll
                for (int d = 32; d >= 1; d >>= 1) s += __shfl_xor(s, d, 64);
                if (lane == 0) part[wvi][bb][1 + oo] = s;
            }
        }
        __syncthreads();
        if (tid < 68) {
            int bb = tid / 17, k = tid % 17;
            float s;
            if (k == 0)
                s = part[0][bb][0] + part[1][bb][0] + part[2][bb][0] + part[3][bb][0];
            else {
                int o = k - 1;
                if (o < 8)
                    s = part[0][bb][1 + o] + part[1][bb][1 + o] +
                        part[2][bb][1 + o] + part[3][bb][1 + o];
                else
                    s = part[4][bb][o - 7] + part[5][bb][o - 7] +
                        part[6][bb][o - 7] + part[7][bb][o - 7];
            }
            sums[bb][k] = s;
        }
        __syncthreads();
        if (tid < 4) {
            float Z = sums[tid][0];
            float s[16];
            float s2 = 0.f;
#pragma unroll
            for (int o = 0; o < 16; ++o) {
                s[o] = sums[tid][1 + o] / Z;
                s2 = fmaf(s[o], s[o], s2);
            }
            float f = (s2 / (1.f + s2)) / sqrtf(s2 + 1e-8f);
#pragma unroll
            for (int o = 0; o < 16; ++o) vsh[tid][o] = f * s[o];
        }
        __syncthreads();
    }
    if (tid < 64) {
        int bb = tid >> 4, o = tid & 15;
        v_out[((size_t)(b0 + bb) * NCLS + c) * 16 + o] = vsh[bb][o];
    }
}

// head: v_length, argmax, one-hot
__global__ __launch_bounds__(64) void k_head(const float* __restrict__ v,
                                             float* __restrict__ out,
                                             int* __restrict__ cls_ws) {
    __shared__ float len2[NCLS];
    __shared__ int cls_sh;
    int b = blockIdx.x, tid = threadIdx.x;
    if (tid < NCLS) {
        float s2 = 0.f;
#pragma unroll
        for (int o = 0; o < 16; ++o) {
            float t = v[((size_t)b * NCLS + tid) * 16 + o];
            s2 = fmaf(t, t, s2);
        }
        len2[tid] = s2;
        out[OUT_LEN + b * NCLS + tid] = sqrtf(s2);
    }
    __syncthreads();
    if (tid == 0) {
        int best = 0;
        float bv = len2[0];
        for (int c2 = 1; c2 < NCLS; ++c2)
            if (len2[c2] > bv) { bv = len2[c2]; best = c2; }
        cls_sh = best;
        cls_ws[b] = best;
    }
    __syncthreads();
    if (tid < NCLS) out[b * NCLS + tid] = (tid == cls_sh) ? 1.0f : 0.0f;
}

// decoder layer 1
__global__ __launch_bounds__(256) void k_dec1(const float* __restrict__ v,
                                              const int* __restrict__ cls_ws,
                                              const float* __restrict__ w1,
                                              const float* __restrict__ b1,
                                              float* __restrict__ h1) {
    int id = blockIdx.x * 256 + threadIdx.x;  // B*512
    int j = id % 512, b = id / 512;
    int cls = cls_ws[b];
    const float* vp = v + ((size_t)b * NCLS + cls) * 16;
    float acc = b1[j];
#pragma unroll
    for (int o = 0; o < 16; ++o)
        acc = fmaf(vp[o], w1[(size_t)(cls * 16 + o) * 512 + j], acc);
    h1[id] = fmaxf(acc, 0.f);
}

// decoder layer 2
__global__ __launch_bounds__(256) void k_dec2(const float* __restrict__ h1,
                                              const float* __restrict__ w2,
                                              const float* __restrict__ b2,
                                              float* __restrict__ h2) {
    __shared__ float hs[512];
    int bi = blockIdx.x;
    int jc = bi % 4;
    int b = bi / 4;
    int tid = threadIdx.x;
    hs[tid] = h1[b * 512 + tid];
    hs[tid + 256] = h1[b * 512 + tid + 256];
    __syncthreads();
    int j = jc * 256 + tid;
    float acc = b2[j];
#pragma unroll 8
    for (int k = 0; k < 512; ++k)
        acc = fmaf(hs[k], w2[(size_t)k * 1024 + j], acc);
    h2[b * 1024 + j] = fmaxf(acc, 0.f);
}

// decoder layer 3 + sigmoid
__global__ __launch_bounds__(256) void k_dec3(const float* __restrict__ h2,
                                              const float* __restrict__ w3,
                                              const float* __restrict__ b3,
                                              float* __restrict__ out) {
    __shared__ float hs[1024];
    int bi = blockIdx.x;
    int jc = bi % 4;
    int b = bi / 4;
    int tid = threadIdx.x;
#pragma unroll
    for (int t = 0; t < 4; ++t) hs[tid + t * 256] = h2[b * 1024 + tid + t * 256];
    __syncthreads();
    int j = jc * 256 + tid;
    if (j < 784) {
        float acc = b3[j];
#pragma unroll 8
        for (int k = 0; k < 1024; ++k)
            acc = fmaf(hs[k], w3[(size_t)k * 784 + j], acc);
        out[OUT_REC + b * 784 + j] = 1.f / (1.f + __expf(-acc));
    }
}

// ---------------- launcher ----------------
extern "C" void kernel_launch(void* const* d_in, const int* in_sizes, int n_in,
                              void* d_out, int out_size, void* d_ws, size_t ws_size,
                              hipStream_t stream) {
    const float* imgs = (const float*)d_in[0];
    const float* c1w  = (const float*)d_in[1];
    const float* c1b  = (const float*)d_in[2];
    const float* c2w  = (const float*)d_in[3];
    const float* c2b  = (const float*)d_in[4];
    const float* Wd   = (const float*)d_in[5];
    const float* dw1  = (const float*)d_in[6];
    const float* db1  = (const float*)d_in[7];
    const float* dw2  = (const float*)d_in[8];
    const float* db2  = (const float*)d_in[9];
    const float* dw3  = (const float*)d_in[10];
    const float* db3  = (const float*)d_in[11];

    float* out = (float*)d_out;
    float* ws  = (float*)d_ws;
    ushort* x1h = (ushort*)(ws + WS_X1H);
    ushort* x1l = (ushort*)(ws + WS_X1L);
    ushort* bpk = (ushort*)(ws + WS_BH);   // 81*131072 ushorts = 21.23 MB
    float* p    = ws + WS_P;
    float* u    = ws + WS_U;
    float* v    = ws + WS_V;
    float* h1   = ws + WS_H1;
    float* h2   = ws + WS_H2;
    int*   cls  = (int*)(ws + WS_CLS);
    float* wtv  = ws + WS_X1H;   // reuses x1h region (dead after k_conv2s)

    k_conv1<<<BB * 20, 256, 0, stream>>>(imgs, c1w, c1b, x1h, x1l);
    k_prep_w2<<<256, 256, 0, stream>>>(c2w, bpk);
    k_conv2s<<<BB * 2, 512, 0, stream>>>(x1h, x1l, bpk, c2b, p);
    k_squash<<<BB * NCAP / 256, 256, 0, stream>>>(p, u);
    k_prep_wt<<<720, 256, 0, stream>>>(Wd, wtv);   // after conv2s: x1h region now free
    k_route8<<<(BB / 4) * NCLS, 512, 0, stream>>>(u, wtv, v);
    k_head<<<BB, 64, 0, stream>>>(v, out, cls);
    k_dec1<<<BB * 512 / 256, 256, 0, stream>>>(v, cls, dw1, db1, h1);
    k_dec2<<<BB * 4, 256, 0, stream>>>(h1, dw2, db2, h2);
    k_dec3<<<BB * 4, 256, 0, stream>>>(h2, dw3, db3, out);
}